// Round 16
// baseline (2926.767 us; speedup 1.0000x reference)
//
#include <hip/hip_runtime.h>
#include <math.h>

#define BATCH 32
#define NNODE 325
#define T_HIST 12
#define T_PRED 12
#define H 256
#define G4 1024
#define ROWS (BATCH*NNODE)
#define MPAD 10496  // 82*128

typedef __attribute__((ext_vector_type(8))) short bf16x8;
typedef __attribute__((ext_vector_type(4))) float f32x4;
typedef unsigned short ushort_t;
typedef unsigned int uint_t;

#define GLL16(gp, sp) __builtin_amdgcn_global_load_lds( \
    (const __attribute__((address_space(1))) void*)(gp), \
    (__attribute__((address_space(3))) void*)(sp), 16, 0, 0)

__device__ inline float bf2f(ushort_t u) { return __uint_as_float(((uint_t)u) << 16); }

__device__ inline void split2(float v, ushort_t& h, ushort_t& l) {
    uint_t b = __float_as_uint(v);
    uint_t hb = (b + 0x7fffu + ((b >> 16) & 1u)) & 0xffff0000u;
    h = (ushort_t)(hb >> 16);
    float r = v - __uint_as_float(hb);
    uint_t rb = __float_as_uint(r);
    l = (ushort_t)((rb + 0x7fffu + ((rb >> 16) & 1u)) >> 16);
}

__device__ inline float sigm(float x) {
    x = fminf(fmaxf(x, -30.f), 30.f);
    return 1.f / (1.f + __expf(-x));
}
__device__ inline float tanh_f(float x) {
    x = fminf(fmaxf(x, -15.f), 15.f);
    float e = __expf(2.f * x);
    return (e - 1.f) / (e + 1.f);
}

// ---------------------------------------------------------------------------
// Weight prep
// ---------------------------------------------------------------------------
__global__ void collapse_kernel(const float* __restrict__ w, float* __restrict__ out,
                                int cin, int nblk) {
    int idx = blockIdx.x * blockDim.x + threadIdx.x;
    if (idx >= cin * H) return;
    int c = idx / H, h = idx % H;
    float s = 0.f;
    for (int k = 0; k < nblk; ++k) s += w[(size_t)(k * cin + c) * H + h];
    out[idx] = s;
}

// Gate-interleaved big pack: col' = 4*j + gate. Layout [32 kg][1024 col'][8].
__global__ void pack_big_kernel(const float* __restrict__ wih, const float* __restrict__ whh,
                                const float* __restrict__ bih, const float* __restrict__ bhh,
                                ushort_t* __restrict__ Bxh, ushort_t* __restrict__ Bxl,
                                ushort_t* __restrict__ Bhh, ushort_t* __restrict__ Bhl,
                                float* __restrict__ biasI) {
    int idx = blockIdx.x * blockDim.x + threadIdx.x;  // 32*1024
    if (idx >= 32 * G4) return;
    int kg = idx >> 10, col = idx & 1023;
    int j = col >> 2, g = col & 3;
    int gcol = g * 256 + j;
    if (kg == 0) biasI[col] = bih[gcol] + bhh[gcol];
#pragma unroll
    for (int jj = 0; jj < 8; ++jj) {
        int k = kg * 8 + jj;
        ushort_t hh, ll;
        split2(wih[(size_t)gcol * H + k], hh, ll);
        Bxh[(size_t)idx * 8 + jj] = hh; Bxl[(size_t)idx * 8 + jj] = ll;
        split2(whh[(size_t)gcol * H + k], hh, ll);
        Bhh[(size_t)idx * 8 + jj] = hh; Bhl[(size_t)idx * 8 + jj] = ll;
    }
}

// Small pack: collapse 5 K-blocks, layout [32 kg][256 n][8] hi/lo.
__global__ void pack_small_kernel(const float* __restrict__ w,
                                  ushort_t* __restrict__ Bh, ushort_t* __restrict__ Bl) {
    int idx = blockIdx.x * blockDim.x + threadIdx.x;  // 32*256
    if (idx >= 32 * H) return;
    int kg = idx >> 8, n = idx & 255;
#pragma unroll
    for (int jj = 0; jj < 8; ++jj) {
        int k = kg * 8 + jj;
        float s = 0.f;
        for (int blk = 0; blk < 5; ++blk) s += w[(size_t)(blk * H + k) * H + n];
        ushort_t hh, ll; split2(s, hh, ll);
        Bh[(size_t)idx * 8 + jj] = hh; Bl[(size_t)idx * 8 + jj] = ll;
    }
}

// ---------------------------------------------------------------------------
// Producers writing k-packed [kg][MPAD][8] hi/lo
// ---------------------------------------------------------------------------
__global__ void enc_pre0_pk(const float* __restrict__ inp, const float* __restrict__ w,
                            const float* __restrict__ b, ushort_t* __restrict__ oh,
                            ushort_t* __restrict__ ol, int t) {
    int m = blockIdx.x * 256 + threadIdx.x;   // grid (41, 32)
    int kg = blockIdx.y;
    float ip0 = 0.f, ip1 = 0.f;
    if (m < ROWS) {
        int bb = m / NNODE, nn = m % NNODE;
        const float* ip = inp + (((size_t)bb * T_HIST + t) * NNODE + nn) * 2;
        ip0 = ip[0]; ip1 = ip[1];
    }
    union { ushort_t u[8]; bf16x8 v; } hc, lc;
#pragma unroll
    for (int jj = 0; jj < 8; ++jj) {
        int j = kg * 8 + jj;
        float v = (m < ROWS) ? fmaxf(ip0 * w[j] + ip1 * w[H + j] + b[j], 0.f) : 0.f;
        split2(v, hc.u[jj], lc.u[jj]);
    }
    size_t base = ((size_t)kg * MPAD + m) * 8;
    *(bf16x8*)&oh[base] = hc.v;
    *(bf16x8*)&ol[base] = lc.v;
}

__global__ void dec_pre0_pk(const float* __restrict__ y, const float* __restrict__ w,
                            const float* __restrict__ b, ushort_t* __restrict__ oh,
                            ushort_t* __restrict__ ol) {
    int m = blockIdx.x * 256 + threadIdx.x;   // grid (41, 32)
    int kg = blockIdx.y;
    float yv = y[m];
    union { ushort_t u[8]; bf16x8 v; } hc, lc;
#pragma unroll
    for (int jj = 0; jj < 8; ++jj) {
        int j = kg * 8 + jj;
        float v = fmaxf(yv * w[j] + b[j], 0.f);
        split2(v, hc.u[jj], lc.u[jj]);
    }
    size_t base = ((size_t)kg * MPAD + m) * 8;
    *(bf16x8*)&oh[base] = hc.v;
    *(bf16x8*)&ol[base] = lc.v;
}

// ---------------------------------------------------------------------------
// r6 GEMM body, factored. PRIO: setprio around MFMA (deep-grid fused kernels
// only — r12/r13 A/B: +10% pairs, −2.5us shallow singles). No K-rotation
// (r14: L2 broadcast loss). Tile 128 x BNT(=64), 4 waves; 2-slot LDS ring
// (48KB, 3 blocks/CU); raw s_barrier + counted vmcnt(6); 12 ds_read_b128
// feed all 3 split-term MFMA groups.
// Swapped operands mfma(B,A): acc[i][j][r]: m = bm+wm*64+i*16+(lane&15),
//   n = bn+wn*32+j*16+(lane>>4)*4+r.
// GATES: gate-interleaved cols (col'=4cell+g) => r-quad = one cell's i,f,g,o.
// ---------------------------------------------------------------------------
template<bool GATES, int NSC, int HSC, int BNT, int NBG, bool PRIO>
__device__ __forceinline__ void gemm_body(
    const ushort_t* AxH, const ushort_t* AxL,
    const ushort_t* AhH, const ushort_t* AhL,
    const ushort_t* BxH, const ushort_t* BxL,
    const ushort_t* BhH, const ushort_t* BhL,
    const float* bias, float* cst,
    ushort_t* OH, ushort_t* OL,
    int nbx, int bid)
{
    constexpr int BCH = BNT * 4;        // B chunks per slot (=256)
    constexpr int JB  = BNT / 32;       // 16-col frags per wave (=2)
    __shared__ __align__(16) ushort_t As[2][2][4096];    // [slot][hi/lo] 8KB each
    __shared__ __align__(16) ushort_t Bs[2][2][BCH * 8]; // [slot][hi/lo] 4KB each

    const int bm = (bid / nbx) * 128, bn = (bid % nbx) * BNT;
    const int tid = threadIdx.x, lane = tid & 63;
    const int wm = (tid >> 7) & 1, wn = (tid >> 6) & 1;
    const int l15 = lane & 15, lk = lane >> 4;

    auto stageSC = [&](int s, int slot) {
        const ushort_t *Ah, *Al, *Bh, *Bl; int ck;
        if (s < HSC) { Ah = AxH; Al = AxL; Bh = BxH; Bl = BxL; ck = s; }
        else         { Ah = AhH; Al = AhL; Bh = BhH; Bl = BhL; ck = s - HSC; }
        // A hi+lo: 512 chunks each (4 kg x 128 rows), 2 units/thread/stream
#pragma unroll
        for (int q = 0; q < 2; ++q) {
            int ubase = (tid & 192) + q * 256;
            int u = ubase + lane;
            int kgl = u >> 7, rc = u & 127;
            size_t ga = ((size_t)(ck * 4 + kgl) * MPAD + bm + rc) * 8;
            GLL16(Ah + ga, &As[slot][0][ubase * 8]);
            GLL16(Al + ga, &As[slot][1][ubase * 8]);
        }
        // B hi+lo: 256 chunks (4 kg x 64 cols), 1 unit/thread/stream
        {
            int ubase = tid & 192;
            int kgl = tid >> 6, nc = tid & 63;
            size_t gb = ((size_t)(ck * 4 + kgl) * NBG + bn + nc) * 8;
            GLL16(Bh + gb, &Bs[slot][0][ubase * 8]);
            GLL16(Bl + gb, &Bs[slot][1][ubase * 8]);
        }
    };

    f32x4 acc[4][JB] = {};

    stageSC(0, 0);   // prologue: 6 gll/thread outstanding

#pragma unroll
    for (int s = 0; s < NSC; ++s) {
        __builtin_amdgcn_s_barrier();            // compute(s-1) done -> slot free
        if (s + 1 < NSC) {
            stageSC(s + 1, (s + 1) & 1);
            asm volatile("s_waitcnt vmcnt(6)" ::: "memory");  // SC(s) landed, SC(s+1) in flight
        } else {
            asm volatile("s_waitcnt vmcnt(0)" ::: "memory");
        }
        __builtin_amdgcn_s_barrier();            // SC(s) visible to all waves
        __builtin_amdgcn_sched_barrier(0);

        const int slot = s & 1;
        bf16x8 ah[4], al[4], bh[JB], bl[JB];
#pragma unroll
        for (int i = 0; i < 4; ++i) {
            int ea = (lk * 128 + wm * 64 + i * 16 + l15) * 8;
            ah[i] = *(const bf16x8*)&As[slot][0][ea];
            al[i] = *(const bf16x8*)&As[slot][1][ea];
        }
#pragma unroll
        for (int j = 0; j < JB; ++j) {
            int eb = (lk * BNT + wn * (BNT / 2) + j * 16 + l15) * 8;
            bh[j] = *(const bf16x8*)&Bs[slot][0][eb];
            bl[j] = *(const bf16x8*)&Bs[slot][1][eb];
        }
        if constexpr (PRIO) __builtin_amdgcn_s_setprio(1);
#pragma unroll
        for (int i = 0; i < 4; ++i)
#pragma unroll
            for (int j = 0; j < JB; ++j)
                acc[i][j] = __builtin_amdgcn_mfma_f32_16x16x32_bf16(bh[j], ah[i], acc[i][j], 0, 0, 0);
#pragma unroll
        for (int i = 0; i < 4; ++i)
#pragma unroll
            for (int j = 0; j < JB; ++j)
                acc[i][j] = __builtin_amdgcn_mfma_f32_16x16x32_bf16(bl[j], ah[i], acc[i][j], 0, 0, 0);
#pragma unroll
        for (int i = 0; i < 4; ++i)
#pragma unroll
            for (int j = 0; j < JB; ++j)
                acc[i][j] = __builtin_amdgcn_mfma_f32_16x16x32_bf16(bh[j], al[i], acc[i][j], 0, 0, 0);
        if constexpr (PRIO) __builtin_amdgcn_s_setprio(0);
    }

    // ---- epilogue ----
    if constexpr (GATES) {
        // n = bn + wn*32 + j*16 + lk*4 + r ; r-quad = gates i,f,g,o of one cell
        uint_t* Hs = (uint_t*)&As[0][0][0];   // 8.7KB scratch; last K step read slot 1
        const int jb0 = (bn >> 2) + wn * 8;
#pragma unroll
        for (int j = 0; j < JB; ++j) {
            float4 b4 = *(const float4*)&bias[bn + wn * 32 + j * 16 + lk * 4];
            int cell = jb0 + j * 4 + lk;
#pragma unroll
            for (int i = 0; i < 4; ++i) {
                int m = bm + wm * 64 + i * 16 + l15;
                float vi = acc[i][j][0] + b4.x;
                float vf = acc[i][j][1] + b4.y;
                float vg = acc[i][j][2] + b4.z;
                float vo = acc[i][j][3] + b4.w;
                size_t ci = (size_t)cell * MPAD + m;
                float cold = cst[ci];
                float cn = sigm(vf) * cold + sigm(vi) * tanh_f(vg);
                float hn = sigm(vo) * tanh_f(cn);
                cst[ci] = cn;
                ushort_t hh, hl; split2(hn, hh, hl);
                Hs[(wm * 64 + i * 16 + l15) * 17 + wn * 8 + j * 4 + lk] = ((uint_t)hh << 16) | hl;
            }
        }
        __syncthreads();
        {
            int mloc = tid & 127, kgl = tid >> 7;   // 2 kg x 128 rows
            union { ushort_t u[8]; bf16x8 v; } hi, lo;
#pragma unroll
            for (int jj = 0; jj < 8; ++jj) {
                uint_t wv = Hs[mloc * 17 + kgl * 8 + jj];
                hi.u[jj] = (ushort_t)(wv >> 16);
                lo.u[jj] = (ushort_t)(wv & 0xffffu);
            }
            size_t base = ((size_t)((bn >> 5) + kgl) * MPAD + bm + mloc) * 8;
            *(bf16x8*)&OH[base] = hi.v;
            *(bf16x8*)&OL[base] = lo.v;
        }
    } else {
        // relu + split, k-packed via lk-pair (xor 16) chunk assembly
#pragma unroll
        for (int j = 0; j < JB; ++j) {
            float4 b4 = *(const float4*)&bias[bn + wn * (BNT / 2) + j * 16 + lk * 4];
#pragma unroll
            for (int i = 0; i < 4; ++i) {
                float v0 = fmaxf(acc[i][j][0] + b4.x, 0.f);
                float v1 = fmaxf(acc[i][j][1] + b4.y, 0.f);
                float v2 = fmaxf(acc[i][j][2] + b4.z, 0.f);
                float v3 = fmaxf(acc[i][j][3] + b4.w, 0.f);
                ushort_t h0, h1, h2, h3, l0, l1, l2, l3;
                split2(v0, h0, l0); split2(v1, h1, l1);
                split2(v2, h2, l2); split2(v3, h3, l3);
                uint_t hu0 = (uint_t)h0 | ((uint_t)h1 << 16), hu1 = (uint_t)h2 | ((uint_t)h3 << 16);
                uint_t lu0 = (uint_t)l0 | ((uint_t)l1 << 16), lu1 = (uint_t)l2 | ((uint_t)l3 << 16);
                uint_t ph0 = (uint_t)__shfl_xor((int)hu0, 16, 64);
                uint_t ph1 = (uint_t)__shfl_xor((int)hu1, 16, 64);
                uint_t pl0 = (uint_t)__shfl_xor((int)lu0, 16, 64);
                uint_t pl1 = (uint_t)__shfl_xor((int)lu1, 16, 64);
                int kgg = ((bn + wn * (BNT / 2) + j * 16) >> 3) + (lk >> 1);
                size_t base = ((size_t)kgg * MPAD + bm + wm * 64 + i * 16 + l15) * 8;
                union { uint_t u2[4]; bf16x8 v; } ch;
                if ((lk & 1) == 0) {
                    ch.u2[0] = hu0; ch.u2[1] = hu1; ch.u2[2] = ph0; ch.u2[3] = ph1;
                    *(bf16x8*)&OH[base] = ch.v;
                } else {
                    ch.u2[0] = pl0; ch.u2[1] = pl1; ch.u2[2] = lu0; ch.u2[3] = lu1;
                    *(bf16x8*)&OL[base] = ch.v;
                }
            }
        }
    }
}

// ---------------------------------------------------------------------------
// Kernels. Singles (big + small): direct args, NO setprio (r6/r13-verified).
// pair3 (encoder): segments {L1(t) big, L0(t+1) big, small(t+2)} — all
// independent streams (parity-audited), setprio ON, XCD swizzle per segment.
// nSmall=0 gives the r13 2-segment pair.
// ---------------------------------------------------------------------------
struct GArgs {
    const ushort_t *AxH, *AxL, *AhH, *AhL;
    const ushort_t *BxH, *BxL, *BhH, *BhL;
    const float* bias;
    float* cst;
    ushort_t *OH, *OL;
};

template<bool GATES, int NSC, int HSC, int BNT, int NBG, int MINW>
__global__ __launch_bounds__(256, MINW) void gemm_k(
    const ushort_t* __restrict__ AxH, const ushort_t* __restrict__ AxL,
    const ushort_t* __restrict__ AhH, const ushort_t* __restrict__ AhL,
    const ushort_t* __restrict__ BxH, const ushort_t* __restrict__ BxL,
    const ushort_t* __restrict__ BhH, const ushort_t* __restrict__ BhL,
    const float* __restrict__ bias, float* __restrict__ cst,
    ushort_t* __restrict__ OH, ushort_t* __restrict__ OL,
    int nbx, int doSwz)
{
    int bid = blockIdx.x;
    if (doSwz) { int cpx = gridDim.x >> 3; bid = (bid & 7) * cpx + (bid >> 3); }
    gemm_body<GATES, NSC, HSC, BNT, NBG, false>(AxH, AxL, AhH, AhL, BxH, BxL, BhH, BhL,
                                                bias, cst, OH, OL, nbx, bid);
}

__global__ __launch_bounds__(256, 3) void gemm_pair3(GArgs a, GArgs b, GArgs sm) {
    int raw = blockIdx.x;
    if (raw < 2624) {
        int sel = raw >= 1312;
        int local = sel ? raw - 1312 : raw;
        int bid = (local & 7) * 164 + (local >> 3);       // XCD swizzle (1312/8=164)
        const GArgs& g = sel ? b : a;
        gemm_body<true, 16, 8, 64, 1024, true>(g.AxH, g.AxL, g.AhH, g.AhL,
                                               g.BxH, g.BxL, g.BhH, g.BhL,
                                               g.bias, g.cst, g.OH, g.OL, 16, bid);
    } else {
        int local = raw - 2624;                            // 328 small blocks
        int bid = (local & 7) * 41 + (local >> 3);         // 328/8 = 41
        gemm_body<false, 8, 8, 64, 256, true>(sm.AxH, sm.AxL, sm.AhH, sm.AhL,
                                              sm.BxH, sm.BxL, sm.BhH, sm.BhL,
                                              sm.bias, sm.cst, sm.OH, sm.OL, 4, bid);
    }
}

// ---------------------------------------------------------------------------
// Fused projection + decoder pre0 (r14/r15-verified numerics).
// ---------------------------------------------------------------------------
__global__ void proj_pre0_kernel(const ushort_t* __restrict__ xh, const ushort_t* __restrict__ xl,
                                 const float* __restrict__ pw, const float* __restrict__ pb,
                                 const float* __restrict__ w, const float* __restrict__ b,
                                 ushort_t* __restrict__ oh, ushort_t* __restrict__ ol,
                                 float* __restrict__ out, int t) {
    int wid = threadIdx.x >> 6, lane = threadIdx.x & 63;
    int r = blockIdx.x * 4 + wid;
    if (r >= ROWS) return;
    const int kg = lane >> 1, sub = (lane & 1) * 4;
    size_t base = ((size_t)kg * MPAD + r) * 8 + sub;
    float s = 0.f;
#pragma unroll
    for (int q = 0; q < 4; ++q) {
        int k = kg * 8 + sub + q;
        s += (bf2f(xh[base + q]) + bf2f(xl[base + q])) * pw[k];
    }
#pragma unroll
    for (int off = 32; off > 0; off >>= 1) s += __shfl_down(s, off, 64);
    float yv = __shfl(s, 0, 64) + pb[0];
    if (lane == 0) {
        int bb = r / NNODE, n = r % NNODE;
        out[((size_t)bb * T_PRED + t) * NNODE + n] = yv;
    }
    union { ushort_t u[4]; uint2 v; } hs, ls;
#pragma unroll
    for (int q = 0; q < 4; ++q) {
        int k = kg * 8 + sub + q;
        float v = fmaxf(yv * w[k] + b[k], 0.f);
        split2(v, hs.u[q], ls.u[q]);
    }
    *(uint2*)&oh[base] = hs.v;
    *(uint2*)&ol[base] = ls.v;
}

// ---------------------------------------------------------------------------
static inline GArgs mkargs(const ushort_t* xH, const ushort_t* xL,
                           const ushort_t* hH, const ushort_t* hL,
                           ushort_t* const* B, const float* bias, float* c,
                           ushort_t* oH, ushort_t* oL) {
    GArgs g;
    g.AxH = xH; g.AxL = xL; g.AhH = hH; g.AhL = hL;
    g.BxH = B[0]; g.BxL = B[1]; g.BhH = B[2]; g.BhL = B[3];
    g.bias = bias; g.cst = c; g.OH = oH; g.OL = oL;
    return g;
}
static inline GArgs mkargs_small(const ushort_t* aH, const ushort_t* aL,
                                 const ushort_t* bH, const ushort_t* bL,
                                 const float* bias, ushort_t* oH, ushort_t* oL) {
    GArgs g;
    g.AxH = aH; g.AxL = aL; g.AhH = aH; g.AhL = aL;
    g.BxH = bH; g.BxL = bL; g.BhH = bH; g.BhL = bL;
    g.bias = bias; g.cst = nullptr; g.OH = oH; g.OL = oL;
    return g;
}
static inline void big_single(const ushort_t* xH, const ushort_t* xL,
                              const ushort_t* hH, const ushort_t* hL,
                              ushort_t* const* B, const float* bias, float* c,
                              ushort_t* oH, ushort_t* oL, hipStream_t s) {
    gemm_k<true, 16, 8, 64, 1024, 3><<<1312, 256, 0, s>>>(
        xH, xL, hH, hL, B[0], B[1], B[2], B[3], bias, c, oH, oL, 16, 1);
}
static inline void gemm_small(const ushort_t* aH, const ushort_t* aL,
                              const ushort_t* bH, const ushort_t* bL, const float* bias,
                              ushort_t* oH, ushort_t* oL, hipStream_t s) {
    gemm_k<false, 8, 8, 64, 256, 3><<<82 * 4, 256, 0, s>>>(
        aH, aL, aH, aL, bH, bL, bH, bL, bias, nullptr, oH, oL, 4, 1);
}

extern "C" void kernel_launch(void* const* d_in, const int* in_sizes, int n_in,
                              void* d_out, int out_size, void* d_ws, size_t ws_size,
                              hipStream_t stream) {
    (void)in_sizes; (void)n_in; (void)out_size; (void)ws_size;

    const float* inputs      = (const float*)d_in[0];
    // d_in[1..7]: adaptive-supports MLP — dead code (returns identity), skipped.
    const float* enc_pre_w0  = (const float*)d_in[8];
    const float* enc_pre_b0  = (const float*)d_in[9];
    const float* enc_pre_w1  = (const float*)d_in[10];
    const float* enc_pre_b1  = (const float*)d_in[11];
    const float* enc_wih     = (const float*)d_in[12];
    const float* enc_whh     = (const float*)d_in[13];
    const float* enc_bih     = (const float*)d_in[14];
    const float* enc_bhh     = (const float*)d_in[15];
    const float* dec_pre_w0  = (const float*)d_in[16];
    const float* dec_pre_b0  = (const float*)d_in[17];
    const float* dec_pre_w1  = (const float*)d_in[18];
    const float* dec_pre_b1  = (const float*)d_in[19];
    const float* dec_wih     = (const float*)d_in[20];
    const float* dec_whh     = (const float*)d_in[21];
    const float* dec_bih     = (const float*)d_in[22];
    const float* dec_bhh     = (const float*)d_in[23];
    const float* dec_post_w0 = (const float*)d_in[24];
    const float* dec_post_b0 = (const float*)d_in[25];
    const float* dec_post_w1 = (const float*)d_in[26];
    const float* dec_post_b1 = (const float*)d_in[27];
    const float* proj_w      = (const float*)d_in[28];
    const float* proj_b      = (const float*)d_in[29];
    float* out = (float*)d_out;

    char* wsb = (char*)d_ws;
    size_t off = 0;
    auto allocF = [&](size_t n) { float* p = (float*)(wsb + off); off += ((n * 4 + 15) & ~(size_t)15); return p; };
    auto allocU = [&](size_t n) { ushort_t* p = (ushort_t*)(wsb + off); off += ((n * 2 + 15) & ~(size_t)15); return p; };

    const size_t BIGW = (size_t)32 * G4 * 8;
    const size_t SMLW = (size_t)32 * H * 8;
    const size_t ACT  = (size_t)32 * MPAD * 8;

    ushort_t* eB0[4]; ushort_t* eB1[4]; ushort_t* dB0[4]; ushort_t* dB1[4];
    for (int q = 0; q < 4; ++q) eB0[q] = allocU(BIGW);
    for (int q = 0; q < 4; ++q) eB1[q] = allocU(BIGW);
    for (int q = 0; q < 4; ++q) dB0[q] = allocU(BIGW);
    for (int q = 0; q < 4; ++q) dB1[q] = allocU(BIGW);
    float* eBI0 = allocF(G4); float* eBI1 = allocF(G4);
    float* dBI0 = allocF(G4); float* dBI1 = allocF(G4);
    ushort_t* eP1h = allocU(SMLW); ushort_t* eP1l = allocU(SMLW);
    ushort_t* dP1h = allocU(SMLW); ushort_t* dP1l = allocU(SMLW);
    ushort_t* po0h = allocU(SMLW); ushort_t* po0l = allocU(SMLW);
    ushort_t* po1h = allocU(SMLW); ushort_t* po1l = allocU(SMLW);
    float* encW0eff = allocF(2 * H);
    float* decPre0eff = allocF(H);
    ushort_t* h0H[2]; ushort_t* h0L[2]; ushort_t* h1H[2]; ushort_t* h1L[2];
    for (int q = 0; q < 2; ++q) { h0H[q] = allocU(ACT); h0L[q] = allocU(ACT); }
    for (int q = 0; q < 2; ++q) { h1H[q] = allocU(ACT); h1L[q] = allocU(ACT); }
    float* c0 = allocF((size_t)H * MPAD);
    float* c1 = allocF((size_t)H * MPAD);
    // encoder xa/xb double-buffered by t-parity (pair3 fusion); decoder
    // aliases slot 0 (encoder complete by then).
    ushort_t* xaH[2]; ushort_t* xaL[2]; ushort_t* xbH[2]; ushort_t* xbL[2];
    for (int q = 0; q < 2; ++q) { xaH[q] = allocU(ACT); xaL[q] = allocU(ACT); }
    for (int q = 0; q < 2; ++q) { xbH[q] = allocU(ACT); xbL[q] = allocU(ACT); }
    float* y = allocF(MPAD);

    const size_t LOFF = (size_t)G4 * H;
    const int EW = 256;

    // ---- weight prep ----
    pack_big_kernel<<<128, EW, 0, stream>>>(enc_wih, enc_whh, enc_bih, enc_bhh,
                                            eB0[0], eB0[1], eB0[2], eB0[3], eBI0);
    pack_big_kernel<<<128, EW, 0, stream>>>(enc_wih + LOFF, enc_whh + LOFF, enc_bih + G4, enc_bhh + G4,
                                            eB1[0], eB1[1], eB1[2], eB1[3], eBI1);
    pack_big_kernel<<<128, EW, 0, stream>>>(dec_wih, dec_whh, dec_bih, dec_bhh,
                                            dB0[0], dB0[1], dB0[2], dB0[3], dBI0);
    pack_big_kernel<<<128, EW, 0, stream>>>(dec_wih + LOFF, dec_whh + LOFF, dec_bih + G4, dec_bhh + G4,
                                            dB1[0], dB1[1], dB1[2], dB1[3], dBI1);
    pack_small_kernel<<<32, EW, 0, stream>>>(enc_pre_w1, eP1h, eP1l);
    pack_small_kernel<<<32, EW, 0, stream>>>(dec_pre_w1, dP1h, dP1l);
    pack_small_kernel<<<32, EW, 0, stream>>>(dec_post_w0, po0h, po0l);
    pack_small_kernel<<<32, EW, 0, stream>>>(dec_post_w1, po1h, po1l);
    collapse_kernel<<<2, EW, 0, stream>>>(enc_pre_w0, encW0eff, 2, 5);
    collapse_kernel<<<1, EW, 0, stream>>>(dec_pre_w0, decPre0eff, 1, 5);

    // ---- init state ----
    for (int q = 0; q < 2; ++q) {
        hipMemsetAsync(h0H[q], 0, ACT * 2, stream); hipMemsetAsync(h0L[q], 0, ACT * 2, stream);
        hipMemsetAsync(h1H[q], 0, ACT * 2, stream); hipMemsetAsync(h1L[q], 0, ACT * 2, stream);
    }
    hipMemsetAsync(c0, 0, (size_t)H * MPAD * 4, stream);
    hipMemsetAsync(c1, 0, (size_t)H * MPAD * 4, stream);
    hipMemsetAsync(y, 0, (size_t)MPAD * 4, stream);

    const dim3 PG(MPAD / 256, 32);

    // ---- encoder ----
    // Parity scheme: pre0(t)/small(t) use xa/xb slot (t&1). L0(t): h0[t&1] ->
    // h0[(t&1)^1]. Pair3(t) = {L1(t), L0(t+1), small(t+2)}:
    //   L1(t): reads h0[pr^1], h1[pr] -> h1[pr^1]         (pr = t&1)
    //   L0(t+1): reads xb[(t+1)&1] = xb[pr^1], h0[pr^1] -> h0[pr]
    //   small(t+2): reads xa[(t+2)&1] = xa[pr] (pre0(t+2) just written),
    //               writes xb[pr] (last read by L0(t) in pair3(t-1) - done).
    // All writes disjoint from all reads within one dispatch.
    enc_pre0_pk<<<PG, EW, 0, stream>>>(inputs, encW0eff, enc_pre_b0, xaH[0], xaL[0], 0);
    gemm_small(xaH[0], xaL[0], eP1h, eP1l, enc_pre_b1, xbH[0], xbL[0], stream);
    enc_pre0_pk<<<PG, EW, 0, stream>>>(inputs, encW0eff, enc_pre_b0, xaH[1], xaL[1], 1);
    gemm_small(xaH[1], xaL[1], eP1h, eP1l, enc_pre_b1, xbH[1], xbL[1], stream);
    big_single(xbH[0], xbL[0], h0H[0], h0L[0], eB0, eBI0, c0, h0H[1], h0L[1], stream);
    for (int t = 0; t < T_HIST - 1; ++t) {
        int pr = t & 1;
        GArgs gL1 = mkargs(h0H[pr ^ 1], h0L[pr ^ 1], h1H[pr], h1L[pr],
                           eB1, eBI1, c1, h1H[pr ^ 1], h1L[pr ^ 1]);
        GArgs gL0 = mkargs(xbH[pr ^ 1], xbL[pr ^ 1], h0H[pr ^ 1], h0L[pr ^ 1],
                           eB0, eBI0, c0, h0H[pr], h0L[pr]);
        if (t + 2 <= T_HIST - 1) {
            enc_pre0_pk<<<PG, EW, 0, stream>>>(inputs, encW0eff, enc_pre_b0,
                                               xaH[pr], xaL[pr], t + 2);
            GArgs gSm = mkargs_small(xaH[pr], xaL[pr], eP1h, eP1l, enc_pre_b1,
                                     xbH[pr], xbL[pr]);
            gemm_pair3<<<2952, 256, 0, stream>>>(gL1, gL0, gSm);
        } else {
            gemm_pair3<<<2624, 256, 0, stream>>>(gL1, gL0, gL0 /*unused*/);
        }
    }
    // final L1(11): pr(11)=1; L0(11) (in pair3(10)) wrote h0[0]; h1 current in h1[1]
    big_single(h0H[0], h0L[0], h1H[1], h1L[1], eB1, eBI1, c1, h1H[0], h1L[0], stream);

    // ---- decoder (strictly sequential; aliases xa/xb slot 0) ----
    dec_pre0_pk<<<PG, EW, 0, stream>>>(y, decPre0eff, dec_pre_b0, xaH[0], xaL[0]);
    for (int d = 0; d < T_PRED; ++d) {
        int pr = d & 1;
        gemm_small(xaH[0], xaL[0], dP1h, dP1l, dec_pre_b1, xbH[0], xbL[0], stream);
        big_single(xbH[0], xbL[0], h0H[pr], h0L[pr], dB0, dBI0, c0,
                   h0H[pr ^ 1], h0L[pr ^ 1], stream);
        big_single(h0H[pr ^ 1], h0L[pr ^ 1], h1H[pr], h1L[pr], dB1, dBI1, c1,
                   h1H[pr ^ 1], h1L[pr ^ 1], stream);
        gemm_small(h1H[pr ^ 1], h1L[pr ^ 1], po0h, po0l, dec_post_b0, xaH[0], xaL[0], stream);
        gemm_small(xaH[0], xaL[0], po1h, po1l, dec_post_b1, xbH[0], xbL[0], stream);
        proj_pre0_kernel<<<(ROWS + 3) / 4, EW, 0, stream>>>(
            xbH[0], xbL[0], proj_w, proj_b, decPre0eff, dec_pre_b0, xaH[0], xaL[0], out, d);
    }
}

// Round 17
// 2275.942 us; speedup vs baseline: 1.2860x; 1.2860x over previous
//
#include <hip/hip_runtime.h>
#include <math.h>

#define BATCH 32
#define NNODE 325
#define T_HIST 12
#define T_PRED 12
#define H 256
#define G4 1024
#define ROWS (BATCH*NNODE)
#define MPAD 10496  // 82*128

typedef __attribute__((ext_vector_type(8))) short bf16x8;
typedef __attribute__((ext_vector_type(4))) float f32x4;
typedef unsigned short ushort_t;
typedef unsigned int uint_t;

#define GLL16(gp, sp) __builtin_amdgcn_global_load_lds( \
    (const __attribute__((address_space(1))) void*)(gp), \
    (__attribute__((address_space(3))) void*)(sp), 16, 0, 0)

__device__ inline float bf2f(ushort_t u) { return __uint_as_float(((uint_t)u) << 16); }

__device__ inline void split2(float v, ushort_t& h, ushort_t& l) {
    uint_t b = __float_as_uint(v);
    uint_t hb = (b + 0x7fffu + ((b >> 16) & 1u)) & 0xffff0000u;
    h = (ushort_t)(hb >> 16);
    float r = v - __uint_as_float(hb);
    uint_t rb = __float_as_uint(r);
    l = (ushort_t)((rb + 0x7fffu + ((rb >> 16) & 1u)) >> 16);
}

__device__ inline float sigm(float x) {
    x = fminf(fmaxf(x, -30.f), 30.f);
    return 1.f / (1.f + __expf(-x));
}
__device__ inline float tanh_f(float x) {
    x = fminf(fmaxf(x, -15.f), 15.f);
    float e = __expf(2.f * x);
    return (e - 1.f) / (e + 1.f);
}

// ---------------------------------------------------------------------------
// Weight prep
// ---------------------------------------------------------------------------
__global__ void collapse_kernel(const float* __restrict__ w, float* __restrict__ out,
                                int cin, int nblk) {
    int idx = blockIdx.x * blockDim.x + threadIdx.x;
    if (idx >= cin * H) return;
    int c = idx / H, h = idx % H;
    float s = 0.f;
    for (int k = 0; k < nblk; ++k) s += w[(size_t)(k * cin + c) * H + h];
    out[idx] = s;
}

// Gate-interleaved big pack: col' = 4*j + gate. Layout [32 kg][1024 col'][8].
__global__ void pack_big_kernel(const float* __restrict__ wih, const float* __restrict__ whh,
                                const float* __restrict__ bih, const float* __restrict__ bhh,
                                ushort_t* __restrict__ Bxh, ushort_t* __restrict__ Bxl,
                                ushort_t* __restrict__ Bhh, ushort_t* __restrict__ Bhl,
                                float* __restrict__ biasI) {
    int idx = blockIdx.x * blockDim.x + threadIdx.x;  // 32*1024
    if (idx >= 32 * G4) return;
    int kg = idx >> 10, col = idx & 1023;
    int j = col >> 2, g = col & 3;
    int gcol = g * 256 + j;
    if (kg == 0) biasI[col] = bih[gcol] + bhh[gcol];
#pragma unroll
    for (int jj = 0; jj < 8; ++jj) {
        int k = kg * 8 + jj;
        ushort_t hh, ll;
        split2(wih[(size_t)gcol * H + k], hh, ll);
        Bxh[(size_t)idx * 8 + jj] = hh; Bxl[(size_t)idx * 8 + jj] = ll;
        split2(whh[(size_t)gcol * H + k], hh, ll);
        Bhh[(size_t)idx * 8 + jj] = hh; Bhl[(size_t)idx * 8 + jj] = ll;
    }
}

// Small pack: collapse 5 K-blocks, layout [32 kg][256 n][8] hi/lo.
__global__ void pack_small_kernel(const float* __restrict__ w,
                                  ushort_t* __restrict__ Bh, ushort_t* __restrict__ Bl) {
    int idx = blockIdx.x * blockDim.x + threadIdx.x;  // 32*256
    if (idx >= 32 * H) return;
    int kg = idx >> 8, n = idx & 255;
#pragma unroll
    for (int jj = 0; jj < 8; ++jj) {
        int k = kg * 8 + jj;
        float s = 0.f;
        for (int blk = 0; blk < 5; ++blk) s += w[(size_t)(blk * H + k) * H + n];
        ushort_t hh, ll; split2(s, hh, ll);
        Bh[(size_t)idx * 8 + jj] = hh; Bl[(size_t)idx * 8 + jj] = ll;
    }
}

// ---------------------------------------------------------------------------
// Producers writing k-packed [kg][MPAD][8] hi/lo
// ---------------------------------------------------------------------------
__global__ void enc_pre0_pk(const float* __restrict__ inp, const float* __restrict__ w,
                            const float* __restrict__ b, ushort_t* __restrict__ oh,
                            ushort_t* __restrict__ ol, int t) {
    int m = blockIdx.x * 256 + threadIdx.x;   // grid (41, 32)
    int kg = blockIdx.y;
    float ip0 = 0.f, ip1 = 0.f;
    if (m < ROWS) {
        int bb = m / NNODE, nn = m % NNODE;
        const float* ip = inp + (((size_t)bb * T_HIST + t) * NNODE + nn) * 2;
        ip0 = ip[0]; ip1 = ip[1];
    }
    union { ushort_t u[8]; bf16x8 v; } hc, lc;
#pragma unroll
    for (int jj = 0; jj < 8; ++jj) {
        int j = kg * 8 + jj;
        float v = (m < ROWS) ? fmaxf(ip0 * w[j] + ip1 * w[H + j] + b[j], 0.f) : 0.f;
        split2(v, hc.u[jj], lc.u[jj]);
    }
    size_t base = ((size_t)kg * MPAD + m) * 8;
    *(bf16x8*)&oh[base] = hc.v;
    *(bf16x8*)&ol[base] = lc.v;
}

__global__ void dec_pre0_pk(const float* __restrict__ y, const float* __restrict__ w,
                            const float* __restrict__ b, ushort_t* __restrict__ oh,
                            ushort_t* __restrict__ ol) {
    int m = blockIdx.x * 256 + threadIdx.x;   // grid (41, 32)
    int kg = blockIdx.y;
    float yv = y[m];
    union { ushort_t u[8]; bf16x8 v; } hc, lc;
#pragma unroll
    for (int jj = 0; jj < 8; ++jj) {
        int j = kg * 8 + jj;
        float v = fmaxf(yv * w[j] + b[j], 0.f);
        split2(v, hc.u[jj], lc.u[jj]);
    }
    size_t base = ((size_t)kg * MPAD + m) * 8;
    *(bf16x8*)&oh[base] = hc.v;
    *(bf16x8*)&ol[base] = lc.v;
}

// ---------------------------------------------------------------------------
// r6 GEMM body, factored; LDS passed in as a pointer so multiple
// instantiations in ONE kernel can ALIAS the same 48KB buffer (round-16
// lesson: two static-__shared__ instantiations SUM to 96KB -> 1 block/CU).
// Layout in smem (ushort units): As[2][2][4096] at 0 (32KB),
// Bs[2][2][1024] at 16384 (16KB). Identical for big and small (BNT=64).
// PRIO: setprio around MFMA (deep-grid fused kernels only).
// Tile 128 x 64, 4 waves; 2-slot ring; raw s_barrier + counted vmcnt(6).
// Swapped operands mfma(B,A): acc[i][j][r]: m = bm+wm*64+i*16+(lane&15),
//   n = bn+wn*32+j*16+(lane>>4)*4+r.
// GATES: gate-interleaved cols (col'=4cell+g) => r-quad = one cell's i,f,g,o.
// ---------------------------------------------------------------------------
template<bool GATES, int NSC, int HSC, int BNT, int NBG, bool PRIO>
__device__ __forceinline__ void gemm_body(
    ushort_t* smem,
    const ushort_t* AxH, const ushort_t* AxL,
    const ushort_t* AhH, const ushort_t* AhL,
    const ushort_t* BxH, const ushort_t* BxL,
    const ushort_t* BhH, const ushort_t* BhL,
    const float* bias, float* cst,
    ushort_t* OH, ushort_t* OL,
    int nbx, int bid)
{
    constexpr int BCH = BNT * 4;        // B chunks per slot (=256)
    constexpr int JB  = BNT / 32;       // 16-col frags per wave (=2)
    // As[slot][hi/lo][4096] ; Bs[slot][hi/lo][BCH*8]
    ushort_t* Asp = smem;                      // 16384 ushorts = 32KB
    ushort_t* Bsp = smem + 16384;              //  8192 ushorts = 16KB
    auto As = [&](int slot, int hl) { return Asp + (slot * 2 + hl) * 4096; };
    auto Bs = [&](int slot, int hl) { return Bsp + (slot * 2 + hl) * (BCH * 8); };

    const int bm = (bid / nbx) * 128, bn = (bid % nbx) * BNT;
    const int tid = threadIdx.x, lane = tid & 63;
    const int wm = (tid >> 7) & 1, wn = (tid >> 6) & 1;
    const int l15 = lane & 15, lk = lane >> 4;

    auto stageSC = [&](int s, int slot) {
        const ushort_t *Ah, *Al, *Bh, *Bl; int ck;
        if (s < HSC) { Ah = AxH; Al = AxL; Bh = BxH; Bl = BxL; ck = s; }
        else         { Ah = AhH; Al = AhL; Bh = BhH; Bl = BhL; ck = s - HSC; }
        // A hi+lo: 512 chunks each (4 kg x 128 rows), 2 units/thread/stream
#pragma unroll
        for (int q = 0; q < 2; ++q) {
            int ubase = (tid & 192) + q * 256;
            int u = ubase + lane;
            int kgl = u >> 7, rc = u & 127;
            size_t ga = ((size_t)(ck * 4 + kgl) * MPAD + bm + rc) * 8;
            GLL16(Ah + ga, As(slot, 0) + ubase * 8);
            GLL16(Al + ga, As(slot, 1) + ubase * 8);
        }
        // B hi+lo: 256 chunks (4 kg x 64 cols), 1 unit/thread/stream
        {
            int ubase = tid & 192;
            int kgl = tid >> 6, nc = tid & 63;
            size_t gb = ((size_t)(ck * 4 + kgl) * NBG + bn + nc) * 8;
            GLL16(Bh + gb, Bs(slot, 0) + ubase * 8);
            GLL16(Bl + gb, Bs(slot, 1) + ubase * 8);
        }
    };

    f32x4 acc[4][JB] = {};

    stageSC(0, 0);   // prologue: 6 gll/thread outstanding

#pragma unroll
    for (int s = 0; s < NSC; ++s) {
        __builtin_amdgcn_s_barrier();            // compute(s-1) done -> slot free
        if (s + 1 < NSC) {
            stageSC(s + 1, (s + 1) & 1);
            asm volatile("s_waitcnt vmcnt(6)" ::: "memory");  // SC(s) landed, SC(s+1) in flight
        } else {
            asm volatile("s_waitcnt vmcnt(0)" ::: "memory");
        }
        __builtin_amdgcn_s_barrier();            // SC(s) visible to all waves
        __builtin_amdgcn_sched_barrier(0);

        const int slot = s & 1;
        bf16x8 ah[4], al[4], bh[JB], bl[JB];
#pragma unroll
        for (int i = 0; i < 4; ++i) {
            int ea = (lk * 128 + wm * 64 + i * 16 + l15) * 8;
            ah[i] = *(const bf16x8*)(As(slot, 0) + ea);
            al[i] = *(const bf16x8*)(As(slot, 1) + ea);
        }
#pragma unroll
        for (int j = 0; j < JB; ++j) {
            int eb = (lk * BNT + wn * (BNT / 2) + j * 16 + l15) * 8;
            bh[j] = *(const bf16x8*)(Bs(slot, 0) + eb);
            bl[j] = *(const bf16x8*)(Bs(slot, 1) + eb);
        }
        if constexpr (PRIO) __builtin_amdgcn_s_setprio(1);
#pragma unroll
        for (int i = 0; i < 4; ++i)
#pragma unroll
            for (int j = 0; j < JB; ++j)
                acc[i][j] = __builtin_amdgcn_mfma_f32_16x16x32_bf16(bh[j], ah[i], acc[i][j], 0, 0, 0);
#pragma unroll
        for (int i = 0; i < 4; ++i)
#pragma unroll
            for (int j = 0; j < JB; ++j)
                acc[i][j] = __builtin_amdgcn_mfma_f32_16x16x32_bf16(bl[j], ah[i], acc[i][j], 0, 0, 0);
#pragma unroll
        for (int i = 0; i < 4; ++i)
#pragma unroll
            for (int j = 0; j < JB; ++j)
                acc[i][j] = __builtin_amdgcn_mfma_f32_16x16x32_bf16(bh[j], al[i], acc[i][j], 0, 0, 0);
        if constexpr (PRIO) __builtin_amdgcn_s_setprio(0);
    }

    // ---- epilogue ----
    if constexpr (GATES) {
        // n = bn + wn*32 + j*16 + lk*4 + r ; r-quad = gates i,f,g,o of one cell
        uint_t* Hs = (uint_t*)smem;   // 8.7KB scratch; last K step read slot 1
        const int jb0 = (bn >> 2) + wn * 8;
#pragma unroll
        for (int j = 0; j < JB; ++j) {
            float4 b4 = *(const float4*)&bias[bn + wn * 32 + j * 16 + lk * 4];
            int cell = jb0 + j * 4 + lk;
#pragma unroll
            for (int i = 0; i < 4; ++i) {
                int m = bm + wm * 64 + i * 16 + l15;
                float vi = acc[i][j][0] + b4.x;
                float vf = acc[i][j][1] + b4.y;
                float vg = acc[i][j][2] + b4.z;
                float vo = acc[i][j][3] + b4.w;
                size_t ci = (size_t)cell * MPAD + m;
                float cold = cst[ci];
                float cn = sigm(vf) * cold + sigm(vi) * tanh_f(vg);
                float hn = sigm(vo) * tanh_f(cn);
                cst[ci] = cn;
                ushort_t hh, hl; split2(hn, hh, hl);
                Hs[(wm * 64 + i * 16 + l15) * 17 + wn * 8 + j * 4 + lk] = ((uint_t)hh << 16) | hl;
            }
        }
        __syncthreads();
        {
            int mloc = tid & 127, kgl = tid >> 7;   // 2 kg x 128 rows
            union { ushort_t u[8]; bf16x8 v; } hi, lo;
#pragma unroll
            for (int jj = 0; jj < 8; ++jj) {
                uint_t wv = Hs[mloc * 17 + kgl * 8 + jj];
                hi.u[jj] = (ushort_t)(wv >> 16);
                lo.u[jj] = (ushort_t)(wv & 0xffffu);
            }
            size_t base = ((size_t)((bn >> 5) + kgl) * MPAD + bm + mloc) * 8;
            *(bf16x8*)&OH[base] = hi.v;
            *(bf16x8*)&OL[base] = lo.v;
        }
    } else {
        // relu + split, k-packed via lk-pair (xor 16) chunk assembly
#pragma unroll
        for (int j = 0; j < JB; ++j) {
            float4 b4 = *(const float4*)&bias[bn + wn * (BNT / 2) + j * 16 + lk * 4];
#pragma unroll
            for (int i = 0; i < 4; ++i) {
                float v0 = fmaxf(acc[i][j][0] + b4.x, 0.f);
                float v1 = fmaxf(acc[i][j][1] + b4.y, 0.f);
                float v2 = fmaxf(acc[i][j][2] + b4.z, 0.f);
                float v3 = fmaxf(acc[i][j][3] + b4.w, 0.f);
                ushort_t h0, h1, h2, h3, l0, l1, l2, l3;
                split2(v0, h0, l0); split2(v1, h1, l1);
                split2(v2, h2, l2); split2(v3, h3, l3);
                uint_t hu0 = (uint_t)h0 | ((uint_t)h1 << 16), hu1 = (uint_t)h2 | ((uint_t)h3 << 16);
                uint_t lu0 = (uint_t)l0 | ((uint_t)l1 << 16), lu1 = (uint_t)l2 | ((uint_t)l3 << 16);
                uint_t ph0 = (uint_t)__shfl_xor((int)hu0, 16, 64);
                uint_t ph1 = (uint_t)__shfl_xor((int)hu1, 16, 64);
                uint_t pl0 = (uint_t)__shfl_xor((int)lu0, 16, 64);
                uint_t pl1 = (uint_t)__shfl_xor((int)lu1, 16, 64);
                int kgg = ((bn + wn * (BNT / 2) + j * 16) >> 3) + (lk >> 1);
                size_t base = ((size_t)kgg * MPAD + bm + wm * 64 + i * 16 + l15) * 8;
                union { uint_t u2[4]; bf16x8 v; } ch;
                if ((lk & 1) == 0) {
                    ch.u2[0] = hu0; ch.u2[1] = hu1; ch.u2[2] = ph0; ch.u2[3] = ph1;
                    *(bf16x8*)&OH[base] = ch.v;
                } else {
                    ch.u2[0] = pl0; ch.u2[1] = pl1; ch.u2[2] = lu0; ch.u2[3] = lu1;
                    *(bf16x8*)&OL[base] = ch.v;
                }
            }
        }
    }
}

// ---------------------------------------------------------------------------
// Kernels. Singles (big + small): static 48KB LDS, direct args, NO setprio
// (r6/r13-verified). pair3 (encoder): {L1(t), L0(t+1), small(t+2)} with ONE
// shared dynamic-LDS buffer (48KB) aliased by both instantiations; setprio ON.
// ---------------------------------------------------------------------------
struct GArgs {
    const ushort_t *AxH, *AxL, *AhH, *AhL;
    const ushort_t *BxH, *BxL, *BhH, *BhL;
    const float* bias;
    float* cst;
    ushort_t *OH, *OL;
};

template<bool GATES, int NSC, int HSC, int BNT, int NBG, int MINW>
__global__ __launch_bounds__(256, MINW) void gemm_k(
    const ushort_t* __restrict__ AxH, const ushort_t* __restrict__ AxL,
    const ushort_t* __restrict__ AhH, const ushort_t* __restrict__ AhL,
    const ushort_t* __restrict__ BxH, const ushort_t* __restrict__ BxL,
    const ushort_t* __restrict__ BhH, const ushort_t* __restrict__ BhL,
    const float* __restrict__ bias, float* __restrict__ cst,
    ushort_t* __restrict__ OH, ushort_t* __restrict__ OL,
    int nbx, int doSwz)
{
    __shared__ __align__(16) ushort_t smem[24576];   // 48KB
    int bid = blockIdx.x;
    if (doSwz) { int cpx = gridDim.x >> 3; bid = (bid & 7) * cpx + (bid >> 3); }
    gemm_body<GATES, NSC, HSC, BNT, NBG, false>(smem, AxH, AxL, AhH, AhL,
                                                BxH, BxL, BhH, BhL,
                                                bias, cst, OH, OL, nbx, bid);
}

__global__ __launch_bounds__(256, 3) void gemm_pair3(GArgs a, GArgs b, GArgs sm) {
    extern __shared__ __align__(16) ushort_t dsm[];   // 48KB dynamic, aliased
    int raw = blockIdx.x;
    if (raw < 2624) {
        int sel = raw >= 1312;
        int local = sel ? raw - 1312 : raw;
        int bid = (local & 7) * 164 + (local >> 3);       // XCD swizzle (1312/8=164)
        const GArgs& g = sel ? b : a;
        gemm_body<true, 16, 8, 64, 1024, true>(dsm, g.AxH, g.AxL, g.AhH, g.AhL,
                                               g.BxH, g.BxL, g.BhH, g.BhL,
                                               g.bias, g.cst, g.OH, g.OL, 16, bid);
    } else {
        int local = raw - 2624;                            // 328 small blocks
        int bid = (local & 7) * 41 + (local >> 3);         // 328/8 = 41
        gemm_body<false, 8, 8, 64, 256, true>(dsm, sm.AxH, sm.AxL, sm.AhH, sm.AhL,
                                              sm.BxH, sm.BxL, sm.BhH, sm.BhL,
                                              sm.bias, sm.cst, sm.OH, sm.OL, 4, bid);
    }
}

// ---------------------------------------------------------------------------
// Fused projection + decoder pre0 (r14/r15-verified numerics).
// ---------------------------------------------------------------------------
__global__ void proj_pre0_kernel(const ushort_t* __restrict__ xh, const ushort_t* __restrict__ xl,
                                 const float* __restrict__ pw, const float* __restrict__ pb,
                                 const float* __restrict__ w, const float* __restrict__ b,
                                 ushort_t* __restrict__ oh, ushort_t* __restrict__ ol,
                                 float* __restrict__ out, int t) {
    int wid = threadIdx.x >> 6, lane = threadIdx.x & 63;
    int r = blockIdx.x * 4 + wid;
    if (r >= ROWS) return;
    const int kg = lane >> 1, sub = (lane & 1) * 4;
    size_t base = ((size_t)kg * MPAD + r) * 8 + sub;
    float s = 0.f;
#pragma unroll
    for (int q = 0; q < 4; ++q) {
        int k = kg * 8 + sub + q;
        s += (bf2f(xh[base + q]) + bf2f(xl[base + q])) * pw[k];
    }
#pragma unroll
    for (int off = 32; off > 0; off >>= 1) s += __shfl_down(s, off, 64);
    float yv = __shfl(s, 0, 64) + pb[0];
    if (lane == 0) {
        int bb = r / NNODE, n = r % NNODE;
        out[((size_t)bb * T_PRED + t) * NNODE + n] = yv;
    }
    union { ushort_t u[4]; uint2 v; } hs, ls;
#pragma unroll
    for (int q = 0; q < 4; ++q) {
        int k = kg * 8 + sub + q;
        float v = fmaxf(yv * w[k] + b[k], 0.f);
        split2(v, hs.u[q], ls.u[q]);
    }
    *(uint2*)&oh[base] = hs.v;
    *(uint2*)&ol[base] = ls.v;
}

// ---------------------------------------------------------------------------
static inline GArgs mkargs(const ushort_t* xH, const ushort_t* xL,
                           const ushort_t* hH, const ushort_t* hL,
                           ushort_t* const* B, const float* bias, float* c,
                           ushort_t* oH, ushort_t* oL) {
    GArgs g;
    g.AxH = xH; g.AxL = xL; g.AhH = hH; g.AhL = hL;
    g.BxH = B[0]; g.BxL = B[1]; g.BhH = B[2]; g.BhL = B[3];
    g.bias = bias; g.cst = c; g.OH = oH; g.OL = oL;
    return g;
}
static inline GArgs mkargs_small(const ushort_t* aH, const ushort_t* aL,
                                 const ushort_t* bH, const ushort_t* bL,
                                 const float* bias, ushort_t* oH, ushort_t* oL) {
    GArgs g;
    g.AxH = aH; g.AxL = aL; g.AhH = aH; g.AhL = aL;
    g.BxH = bH; g.BxL = bL; g.BhH = bH; g.BhL = bL;
    g.bias = bias; g.cst = nullptr; g.OH = oH; g.OL = oL;
    return g;
}
static inline void big_single(const ushort_t* xH, const ushort_t* xL,
                              const ushort_t* hH, const ushort_t* hL,
                              ushort_t* const* B, const float* bias, float* c,
                              ushort_t* oH, ushort_t* oL, hipStream_t s) {
    gemm_k<true, 16, 8, 64, 1024, 3><<<1312, 256, 0, s>>>(
        xH, xL, hH, hL, B[0], B[1], B[2], B[3], bias, c, oH, oL, 16, 1);
}
static inline void gemm_small(const ushort_t* aH, const ushort_t* aL,
                              const ushort_t* bH, const ushort_t* bL, const float* bias,
                              ushort_t* oH, ushort_t* oL, hipStream_t s) {
    gemm_k<false, 8, 8, 64, 256, 3><<<82 * 4, 256, 0, s>>>(
        aH, aL, aH, aL, bH, bL, bH, bL, bias, nullptr, oH, oL, 4, 1);
}

extern "C" void kernel_launch(void* const* d_in, const int* in_sizes, int n_in,
                              void* d_out, int out_size, void* d_ws, size_t ws_size,
                              hipStream_t stream) {
    (void)in_sizes; (void)n_in; (void)out_size; (void)ws_size;

    const float* inputs      = (const float*)d_in[0];
    // d_in[1..7]: adaptive-supports MLP — dead code (returns identity), skipped.
    const float* enc_pre_w0  = (const float*)d_in[8];
    const float* enc_pre_b0  = (const float*)d_in[9];
    const float* enc_pre_w1  = (const float*)d_in[10];
    const float* enc_pre_b1  = (const float*)d_in[11];
    const float* enc_wih     = (const float*)d_in[12];
    const float* enc_whh     = (const float*)d_in[13];
    const float* enc_bih     = (const float*)d_in[14];
    const float* enc_bhh     = (const float*)d_in[15];
    const float* dec_pre_w0  = (const float*)d_in[16];
    const float* dec_pre_b0  = (const float*)d_in[17];
    const float* dec_pre_w1  = (const float*)d_in[18];
    const float* dec_pre_b1  = (const float*)d_in[19];
    const float* dec_wih     = (const float*)d_in[20];
    const float* dec_whh     = (const float*)d_in[21];
    const float* dec_bih     = (const float*)d_in[22];
    const float* dec_bhh     = (const float*)d_in[23];
    const float* dec_post_w0 = (const float*)d_in[24];
    const float* dec_post_b0 = (const float*)d_in[25];
    const float* dec_post_w1 = (const float*)d_in[26];
    const float* dec_post_b1 = (const float*)d_in[27];
    const float* proj_w      = (const float*)d_in[28];
    const float* proj_b      = (const float*)d_in[29];
    float* out = (float*)d_out;

    char* wsb = (char*)d_ws;
    size_t off = 0;
    auto allocF = [&](size_t n) { float* p = (float*)(wsb + off); off += ((n * 4 + 15) & ~(size_t)15); return p; };
    auto allocU = [&](size_t n) { ushort_t* p = (ushort_t*)(wsb + off); off += ((n * 2 + 15) & ~(size_t)15); return p; };

    const size_t BIGW = (size_t)32 * G4 * 8;
    const size_t SMLW = (size_t)32 * H * 8;
    const size_t ACT  = (size_t)32 * MPAD * 8;

    ushort_t* eB0[4]; ushort_t* eB1[4]; ushort_t* dB0[4]; ushort_t* dB1[4];
    for (int q = 0; q < 4; ++q) eB0[q] = allocU(BIGW);
    for (int q = 0; q < 4; ++q) eB1[q] = allocU(BIGW);
    for (int q = 0; q < 4; ++q) dB0[q] = allocU(BIGW);
    for (int q = 0; q < 4; ++q) dB1[q] = allocU(BIGW);
    float* eBI0 = allocF(G4); float* eBI1 = allocF(G4);
    float* dBI0 = allocF(G4); float* dBI1 = allocF(G4);
    ushort_t* eP1h = allocU(SMLW); ushort_t* eP1l = allocU(SMLW);
    ushort_t* dP1h = allocU(SMLW); ushort_t* dP1l = allocU(SMLW);
    ushort_t* po0h = allocU(SMLW); ushort_t* po0l = allocU(SMLW);
    ushort_t* po1h = allocU(SMLW); ushort_t* po1l = allocU(SMLW);
    float* encW0eff = allocF(2 * H);
    float* decPre0eff = allocF(H);
    ushort_t* h0H[2]; ushort_t* h0L[2]; ushort_t* h1H[2]; ushort_t* h1L[2];
    for (int q = 0; q < 2; ++q) { h0H[q] = allocU(ACT); h0L[q] = allocU(ACT); }
    for (int q = 0; q < 2; ++q) { h1H[q] = allocU(ACT); h1L[q] = allocU(ACT); }
    float* c0 = allocF((size_t)H * MPAD);
    float* c1 = allocF((size_t)H * MPAD);
    ushort_t* xaH[2]; ushort_t* xaL[2]; ushort_t* xbH[2]; ushort_t* xbL[2];
    for (int q = 0; q < 2; ++q) { xaH[q] = allocU(ACT); xaL[q] = allocU(ACT); }
    for (int q = 0; q < 2; ++q) { xbH[q] = allocU(ACT); xbL[q] = allocU(ACT); }
    float* y = allocF(MPAD);

    const size_t LOFF = (size_t)G4 * H;
    const int EW = 256;

    // ---- weight prep ----
    pack_big_kernel<<<128, EW, 0, stream>>>(enc_wih, enc_whh, enc_bih, enc_bhh,
                                            eB0[0], eB0[1], eB0[2], eB0[3], eBI0);
    pack_big_kernel<<<128, EW, 0, stream>>>(enc_wih + LOFF, enc_whh + LOFF, enc_bih + G4, enc_bhh + G4,
                                            eB1[0], eB1[1], eB1[2], eB1[3], eBI1);
    pack_big_kernel<<<128, EW, 0, stream>>>(dec_wih, dec_whh, dec_bih, dec_bhh,
                                            dB0[0], dB0[1], dB0[2], dB0[3], dBI0);
    pack_big_kernel<<<128, EW, 0, stream>>>(dec_wih + LOFF, dec_whh + LOFF, dec_bih + G4, dec_bhh + G4,
                                            dB1[0], dB1[1], dB1[2], dB1[3], dBI1);
    pack_small_kernel<<<32, EW, 0, stream>>>(enc_pre_w1, eP1h, eP1l);
    pack_small_kernel<<<32, EW, 0, stream>>>(dec_pre_w1, dP1h, dP1l);
    pack_small_kernel<<<32, EW, 0, stream>>>(dec_post_w0, po0h, po0l);
    pack_small_kernel<<<32, EW, 0, stream>>>(dec_post_w1, po1h, po1l);
    collapse_kernel<<<2, EW, 0, stream>>>(enc_pre_w0, encW0eff, 2, 5);
    collapse_kernel<<<1, EW, 0, stream>>>(dec_pre_w0, decPre0eff, 1, 5);

    // ---- init state ----
    for (int q = 0; q < 2; ++q) {
        hipMemsetAsync(h0H[q], 0, ACT * 2, stream); hipMemsetAsync(h0L[q], 0, ACT * 2, stream);
        hipMemsetAsync(h1H[q], 0, ACT * 2, stream); hipMemsetAsync(h1L[q], 0, ACT * 2, stream);
    }
    hipMemsetAsync(c0, 0, (size_t)H * MPAD * 4, stream);
    hipMemsetAsync(c1, 0, (size_t)H * MPAD * 4, stream);
    hipMemsetAsync(y, 0, (size_t)MPAD * 4, stream);

    const dim3 PG(MPAD / 256, 32);

    // ---- encoder ----
    // Parity scheme (r16-audited): pre0(t)/small(t) use xa/xb slot (t&1).
    // Pair3(t) = {L1(t), L0(t+1), small(t+2)}: all writes disjoint from reads.
    enc_pre0_pk<<<PG, EW, 0, stream>>>(inputs, encW0eff, enc_pre_b0, xaH[0], xaL[0], 0);
    gemm_small(xaH[0], xaL[0], eP1h, eP1l, enc_pre_b1, xbH[0], xbL[0], stream);
    enc_pre0_pk<<<PG, EW, 0, stream>>>(inputs, encW0eff, enc_pre_b0, xaH[1], xaL[1], 1);
    gemm_small(xaH[1], xaL[1], eP1h, eP1l, enc_pre_b1, xbH[1], xbL[1], stream);
    big_single(xbH[0], xbL[0], h0H[0], h0L[0], eB0, eBI0, c0, h0H[1], h0L[1], stream);
    for (int t = 0; t < T_HIST - 1; ++t) {
        int pr = t & 1;
        GArgs gL1 = mkargs(h0H[pr ^ 1], h0L[pr ^ 1], h1H[pr], h1L[pr],
                           eB1, eBI1, c1, h1H[pr ^ 1], h1L[pr ^ 1]);
        GArgs gL0 = mkargs(xbH[pr ^ 1], xbL[pr ^ 1], h0H[pr ^ 1], h0L[pr ^ 1],
                           eB0, eBI0, c0, h0H[pr], h0L[pr]);
        if (t + 2 <= T_HIST - 1) {
            enc_pre0_pk<<<PG, EW, 0, stream>>>(inputs, encW0eff, enc_pre_b0,
                                               xaH[pr], xaL[pr], t + 2);
            GArgs gSm = mkargs_small(xaH[pr], xaL[pr], eP1h, eP1l, enc_pre_b1,
                                     xbH[pr], xbL[pr]);
            gemm_pair3<<<2952, 256, 49152, stream>>>(gL1, gL0, gSm);
        } else {
            gemm_pair3<<<2624, 256, 49152, stream>>>(gL1, gL0, gL0 /*unused*/);
        }
    }
    // final L1(11): pr(11)=1; L0(11) (in pair3(10)) wrote h0[0]; h1 current in h1[1]
    big_single(h0H[0], h0L[0], h1H[1], h1L[1], eB1, eBI1, c1, h1H[0], h1L[0], stream);

    // ---- decoder (strictly sequential; aliases xa/xb slot 0) ----
    dec_pre0_pk<<<PG, EW, 0, stream>>>(y, decPre0eff, dec_pre_b0, xaH[0], xaL[0]);
    for (int d = 0; d < T_PRED; ++d) {
        int pr = d & 1;
        gemm_small(xaH[0], xaL[0], dP1h, dP1l, dec_pre_b1, xbH[0], xbL[0], stream);
        big_single(xbH[0], xbL[0], h0H[pr], h0L[pr], dB0, dBI0, c0,
                   h0H[pr ^ 1], h0L[pr ^ 1], stream);
        big_single(h0H[pr ^ 1], h0L[pr ^ 1], h1H[pr], h1L[pr], dB1, dBI1, c1,
                   h1H[pr ^ 1], h1L[pr ^ 1], stream);
        gemm_small(h1H[pr ^ 1], h1L[pr ^ 1], po0h, po0l, dec_post_b0, xaH[0], xaL[0], stream);
        gemm_small(xaH[0], xaL[0], po1h, po1l, dec_post_b1, xbH[0], xbL[0], stream);
        proj_pre0_kernel<<<(ROWS + 3) / 4, EW, 0, stream>>>(
            xbH[0], xbL[0], proj_w, proj_b, decPre0eff, dec_pre_b0, xaH[0], xaL[0], out, d);
    }
}

// Round 19
// 2252.870 us; speedup vs baseline: 1.2991x; 1.0102x over previous
//
#include <hip/hip_runtime.h>
#include <math.h>

#define BATCH 32
#define NNODE 325
#define T_HIST 12
#define T_PRED 12
#define H 256
#define G4 1024
#define ROWS (BATCH*NNODE)
#define MPAD 10496  // 82*128

typedef __attribute__((ext_vector_type(8))) short bf16x8;
typedef __attribute__((ext_vector_type(4))) float f32x4;
typedef unsigned short ushort_t;
typedef unsigned int uint_t;

#define GLL16(gp, sp) __builtin_amdgcn_global_load_lds( \
    (const __attribute__((address_space(1))) void*)(gp), \
    (__attribute__((address_space(3))) void*)(sp), 16, 0, 0)

__device__ inline float bf2f(ushort_t u) { return __uint_as_float(((uint_t)u) << 16); }

__device__ inline void split2(float v, ushort_t& h, ushort_t& l) {
    uint_t b = __float_as_uint(v);
    uint_t hb = (b + 0x7fffu + ((b >> 16) & 1u)) & 0xffff0000u;
    h = (ushort_t)(hb >> 16);
    float r = v - __uint_as_float(hb);
    uint_t rb = __float_as_uint(r);
    l = (ushort_t)((rb + 0x7fffu + ((rb >> 16) & 1u)) >> 16);
}

__device__ inline float sigm(float x) {
    x = fminf(fmaxf(x, -30.f), 30.f);
    return 1.f / (1.f + __expf(-x));
}
__device__ inline float tanh_f(float x) {
    x = fminf(fmaxf(x, -15.f), 15.f);
    float e = __expf(2.f * x);
    return (e - 1.f) / (e + 1.f);
}

// ---------------------------------------------------------------------------
// Weight prep
// ---------------------------------------------------------------------------
__global__ void collapse_kernel(const float* __restrict__ w, float* __restrict__ out,
                                int cin, int nblk) {
    int idx = blockIdx.x * blockDim.x + threadIdx.x;
    if (idx >= cin * H) return;
    int c = idx / H, h = idx % H;
    float s = 0.f;
    for (int k = 0; k < nblk; ++k) s += w[(size_t)(k * cin + c) * H + h];
    out[idx] = s;
}

// Gate-interleaved big pack: col' = 4*j + gate. Layout [32 kg][1024 col'][8].
__global__ void pack_big_kernel(const float* __restrict__ wih, const float* __restrict__ whh,
                                const float* __restrict__ bih, const float* __restrict__ bhh,
                                ushort_t* __restrict__ Bxh, ushort_t* __restrict__ Bxl,
                                ushort_t* __restrict__ Bhh, ushort_t* __restrict__ Bhl,
                                float* __restrict__ biasI) {
    int idx = blockIdx.x * blockDim.x + threadIdx.x;  // 32*1024
    if (idx >= 32 * G4) return;
    int kg = idx >> 10, col = idx & 1023;
    int j = col >> 2, g = col & 3;
    int gcol = g * 256 + j;
    if (kg == 0) biasI[col] = bih[gcol] + bhh[gcol];
#pragma unroll
    for (int jj = 0; jj < 8; ++jj) {
        int k = kg * 8 + jj;
        ushort_t hh, ll;
        split2(wih[(size_t)gcol * H + k], hh, ll);
        Bxh[(size_t)idx * 8 + jj] = hh; Bxl[(size_t)idx * 8 + jj] = ll;
        split2(whh[(size_t)gcol * H + k], hh, ll);
        Bhh[(size_t)idx * 8 + jj] = hh; Bhl[(size_t)idx * 8 + jj] = ll;
    }
}

// Small pack: collapse 5 K-blocks, layout [32 kg][256 n][8] hi/lo.
__global__ void pack_small_kernel(const float* __restrict__ w,
                                  ushort_t* __restrict__ Bh, ushort_t* __restrict__ Bl) {
    int idx = blockIdx.x * blockDim.x + threadIdx.x;  // 32*256
    if (idx >= 32 * H) return;
    int kg = idx >> 8, n = idx & 255;
#pragma unroll
    for (int jj = 0; jj < 8; ++jj) {
        int k = kg * 8 + jj;
        float s = 0.f;
        for (int blk = 0; blk < 5; ++blk) s += w[(size_t)(blk * H + k) * H + n];
        ushort_t hh, ll; split2(s, hh, ll);
        Bh[(size_t)idx * 8 + jj] = hh; Bl[(size_t)idx * 8 + jj] = ll;
    }
}

// ---------------------------------------------------------------------------
// Producers writing k-packed [kg][MPAD][8] hi/lo
// ---------------------------------------------------------------------------
__global__ void enc_pre0_pk(const float* __restrict__ inp, const float* __restrict__ w,
                            const float* __restrict__ b, ushort_t* __restrict__ oh,
                            ushort_t* __restrict__ ol, int t) {
    int m = blockIdx.x * 256 + threadIdx.x;   // grid (41, 32)
    int kg = blockIdx.y;
    float ip0 = 0.f, ip1 = 0.f;
    if (m < ROWS) {
        int bb = m / NNODE, nn = m % NNODE;
        const float* ip = inp + (((size_t)bb * T_HIST + t) * NNODE + nn) * 2;
        ip0 = ip[0]; ip1 = ip[1];
    }
    union { ushort_t u[8]; bf16x8 v; } hc, lc;
#pragma unroll
    for (int jj = 0; jj < 8; ++jj) {
        int j = kg * 8 + jj;
        float v = (m < ROWS) ? fmaxf(ip0 * w[j] + ip1 * w[H + j] + b[j], 0.f) : 0.f;
        split2(v, hc.u[jj], lc.u[jj]);
    }
    size_t base = ((size_t)kg * MPAD + m) * 8;
    *(bf16x8*)&oh[base] = hc.v;
    *(bf16x8*)&ol[base] = lc.v;
}

// ---------------------------------------------------------------------------
// r6 GEMM body, factored; LDS passed in (aliasing across instantiations —
// round-16 lesson: static __shared__ per instantiation SUMS). Layout:
// As[2][2][4096] at 0 (32KB), Bs[2][2][1024] at 16384 (16KB). PRIO: setprio
// around MFMA (deep-grid fused kernels only). Tile 128x64, 4 waves; 2-slot
// ring; raw s_barrier + counted vmcnt(6).
// Swapped operands mfma(B,A): acc[i][j][r]: m = bm+wm*64+i*16+(lane&15),
//   n = bn+wn*32+j*16+(lane>>4)*4+r.
// GATES: gate-interleaved cols (col'=4cell+g) => r-quad = one cell's i,f,g,o.
// ---------------------------------------------------------------------------
template<bool GATES, int NSC, int HSC, int BNT, int NBG, bool PRIO>
__device__ __forceinline__ void gemm_body(
    ushort_t* smem,
    const ushort_t* AxH, const ushort_t* AxL,
    const ushort_t* AhH, const ushort_t* AhL,
    const ushort_t* BxH, const ushort_t* BxL,
    const ushort_t* BhH, const ushort_t* BhL,
    const float* bias, float* cst,
    ushort_t* OH, ushort_t* OL,
    int nbx, int bid)
{
    constexpr int BCH = BNT * 4;        // B chunks per slot (=256)
    constexpr int JB  = BNT / 32;       // 16-col frags per wave (=2)
    ushort_t* Asp = smem;                      // 16384 ushorts = 32KB
    ushort_t* Bsp = smem + 16384;              //  8192 ushorts = 16KB
    auto As = [&](int slot, int hl) { return Asp + (slot * 2 + hl) * 4096; };
    auto Bs = [&](int slot, int hl) { return Bsp + (slot * 2 + hl) * (BCH * 8); };

    const int bm = (bid / nbx) * 128, bn = (bid % nbx) * BNT;
    const int tid = threadIdx.x, lane = tid & 63;
    const int wm = (tid >> 7) & 1, wn = (tid >> 6) & 1;
    const int l15 = lane & 15, lk = lane >> 4;

    auto stageSC = [&](int s, int slot) {
        const ushort_t *Ah, *Al, *Bh, *Bl; int ck;
        if (s < HSC) { Ah = AxH; Al = AxL; Bh = BxH; Bl = BxL; ck = s; }
        else         { Ah = AhH; Al = AhL; Bh = BhH; Bl = BhL; ck = s - HSC; }
#pragma unroll
        for (int q = 0; q < 2; ++q) {
            int ubase = (tid & 192) + q * 256;
            int u = ubase + lane;
            int kgl = u >> 7, rc = u & 127;
            size_t ga = ((size_t)(ck * 4 + kgl) * MPAD + bm + rc) * 8;
            GLL16(Ah + ga, As(slot, 0) + ubase * 8);
            GLL16(Al + ga, As(slot, 1) + ubase * 8);
        }
        {
            int ubase = tid & 192;
            int kgl = tid >> 6, nc = tid & 63;
            size_t gb = ((size_t)(ck * 4 + kgl) * NBG + bn + nc) * 8;
            GLL16(Bh + gb, Bs(slot, 0) + ubase * 8);
            GLL16(Bl + gb, Bs(slot, 1) + ubase * 8);
        }
    };

    f32x4 acc[4][JB] = {};

    stageSC(0, 0);   // prologue: 6 gll/thread outstanding

#pragma unroll
    for (int s = 0; s < NSC; ++s) {
        __builtin_amdgcn_s_barrier();            // compute(s-1) done -> slot free
        if (s + 1 < NSC) {
            stageSC(s + 1, (s + 1) & 1);
            asm volatile("s_waitcnt vmcnt(6)" ::: "memory");  // SC(s) landed
        } else {
            asm volatile("s_waitcnt vmcnt(0)" ::: "memory");
        }
        __builtin_amdgcn_s_barrier();            // SC(s) visible to all waves
        __builtin_amdgcn_sched_barrier(0);

        const int slot = s & 1;
        bf16x8 ah[4], al[4], bh[JB], bl[JB];
#pragma unroll
        for (int i = 0; i < 4; ++i) {
            int ea = (lk * 128 + wm * 64 + i * 16 + l15) * 8;
            ah[i] = *(const bf16x8*)(As(slot, 0) + ea);
            al[i] = *(const bf16x8*)(As(slot, 1) + ea);
        }
#pragma unroll
        for (int j = 0; j < JB; ++j) {
            int eb = (lk * BNT + wn * (BNT / 2) + j * 16 + l15) * 8;
            bh[j] = *(const bf16x8*)(Bs(slot, 0) + eb);
            bl[j] = *(const bf16x8*)(Bs(slot, 1) + eb);
        }
        if constexpr (PRIO) __builtin_amdgcn_s_setprio(1);
#pragma unroll
        for (int i = 0; i < 4; ++i)
#pragma unroll
            for (int j = 0; j < JB; ++j)
                acc[i][j] = __builtin_amdgcn_mfma_f32_16x16x32_bf16(bh[j], ah[i], acc[i][j], 0, 0, 0);
#pragma unroll
        for (int i = 0; i < 4; ++i)
#pragma unroll
            for (int j = 0; j < JB; ++j)
                acc[i][j] = __builtin_amdgcn_mfma_f32_16x16x32_bf16(bl[j], ah[i], acc[i][j], 0, 0, 0);
#pragma unroll
        for (int i = 0; i < 4; ++i)
#pragma unroll
            for (int j = 0; j < JB; ++j)
                acc[i][j] = __builtin_amdgcn_mfma_f32_16x16x32_bf16(bh[j], al[i], acc[i][j], 0, 0, 0);
        if constexpr (PRIO) __builtin_amdgcn_s_setprio(0);
    }

    // ---- epilogue ----
    if constexpr (GATES) {
        uint_t* Hs = (uint_t*)smem;   // 8.7KB scratch; last K step read slot 1
        const int jb0 = (bn >> 2) + wn * 8;
#pragma unroll
        for (int j = 0; j < JB; ++j) {
            float4 b4 = *(const float4*)&bias[bn + wn * 32 + j * 16 + lk * 4];
            int cell = jb0 + j * 4 + lk;
#pragma unroll
            for (int i = 0; i < 4; ++i) {
                int m = bm + wm * 64 + i * 16 + l15;
                float vi = acc[i][j][0] + b4.x;
                float vf = acc[i][j][1] + b4.y;
                float vg = acc[i][j][2] + b4.z;
                float vo = acc[i][j][3] + b4.w;
                size_t ci = (size_t)cell * MPAD + m;
                float cold = cst[ci];
                float cn = sigm(vf) * cold + sigm(vi) * tanh_f(vg);
                float hn = sigm(vo) * tanh_f(cn);
                cst[ci] = cn;
                ushort_t hh, hl; split2(hn, hh, hl);
                Hs[(wm * 64 + i * 16 + l15) * 17 + wn * 8 + j * 4 + lk] = ((uint_t)hh << 16) | hl;
            }
        }
        __syncthreads();
        {
            int mloc = tid & 127, kgl = tid >> 7;   // 2 kg x 128 rows
            union { ushort_t u[8]; bf16x8 v; } hi, lo;
#pragma unroll
            for (int jj = 0; jj < 8; ++jj) {
                uint_t wv = Hs[mloc * 17 + kgl * 8 + jj];
                hi.u[jj] = (ushort_t)(wv >> 16);
                lo.u[jj] = (ushort_t)(wv & 0xffffu);
            }
            size_t base = ((size_t)((bn >> 5) + kgl) * MPAD + bm + mloc) * 8;
            *(bf16x8*)&OH[base] = hi.v;
            *(bf16x8*)&OL[base] = lo.v;
        }
    } else {
#pragma unroll
        for (int j = 0; j < JB; ++j) {
            float4 b4 = *(const float4*)&bias[bn + wn * (BNT / 2) + j * 16 + lk * 4];
#pragma unroll
            for (int i = 0; i < 4; ++i) {
                float v0 = fmaxf(acc[i][j][0] + b4.x, 0.f);
                float v1 = fmaxf(acc[i][j][1] + b4.y, 0.f);
                float v2 = fmaxf(acc[i][j][2] + b4.z, 0.f);
                float v3 = fmaxf(acc[i][j][3] + b4.w, 0.f);
                ushort_t h0, h1, h2, h3, l0, l1, l2, l3;
                split2(v0, h0, l0); split2(v1, h1, l1);
                split2(v2, h2, l2); split2(v3, h3, l3);
                uint_t hu0 = (uint_t)h0 | ((uint_t)h1 << 16), hu1 = (uint_t)h2 | ((uint_t)h3 << 16);
                uint_t lu0 = (uint_t)l0 | ((uint_t)l1 << 16), lu1 = (uint_t)l2 | ((uint_t)l3 << 16);
                uint_t ph0 = (uint_t)__shfl_xor((int)hu0, 16, 64);
                uint_t ph1 = (uint_t)__shfl_xor((int)hu1, 16, 64);
                uint_t pl0 = (uint_t)__shfl_xor((int)lu0, 16, 64);
                uint_t pl1 = (uint_t)__shfl_xor((int)lu1, 16, 64);
                int kgg = ((bn + wn * (BNT / 2) + j * 16) >> 3) + (lk >> 1);
                size_t base = ((size_t)kgg * MPAD + bm + wm * 64 + i * 16 + l15) * 8;
                union { uint_t u2[4]; bf16x8 v; } ch;
                if ((lk & 1) == 0) {
                    ch.u2[0] = hu0; ch.u2[1] = hu1; ch.u2[2] = ph0; ch.u2[3] = ph1;
                    *(bf16x8*)&OH[base] = ch.v;
                } else {
                    ch.u2[0] = pl0; ch.u2[1] = pl1; ch.u2[2] = lu0; ch.u2[3] = lu1;
                    *(bf16x8*)&OL[base] = ch.v;
                }
            }
        }
    }
}

// ---------------------------------------------------------------------------
// Kernels. Singles: static 48KB LDS, direct args, NO setprio (r6-verified).
// gemm_fused: up to 4 segments {big a, big b, small, pre0} in one dispatch,
// ONE aliased dynamic-LDS buffer (48KB), setprio ON for GEMM segments.
// Segment layout: [0,nBigBlk) bigs (a then b), [nBigBlk, +nSmBlk) small,
// rest = 1312 pre0 blocks (elementwise producer; enc-form if peInp != null,
// dec-form (reads peY) otherwise). All segments stream-independent (audited).
// ---------------------------------------------------------------------------
struct GArgs {
    const ushort_t *AxH, *AxL, *AhH, *AhL;
    const ushort_t *BxH, *BxL, *BhH, *BhL;
    const float* bias;
    float* cst;
    ushort_t *OH, *OL;
};

template<bool GATES, int NSC, int HSC, int BNT, int NBG, int MINW>
__global__ __launch_bounds__(256, MINW) void gemm_k(
    const ushort_t* __restrict__ AxH, const ushort_t* __restrict__ AxL,
    const ushort_t* __restrict__ AhH, const ushort_t* __restrict__ AhL,
    const ushort_t* __restrict__ BxH, const ushort_t* __restrict__ BxL,
    const ushort_t* __restrict__ BhH, const ushort_t* __restrict__ BhL,
    const float* __restrict__ bias, float* __restrict__ cst,
    ushort_t* __restrict__ OH, ushort_t* __restrict__ OL,
    int nbx, int doSwz)
{
    __shared__ __align__(16) ushort_t smem[24576];   // 48KB
    int bid = blockIdx.x;
    if (doSwz) { int cpx = gridDim.x >> 3; bid = (bid & 7) * cpx + (bid >> 3); }
    gemm_body<GATES, NSC, HSC, BNT, NBG, false>(smem, AxH, AxL, AhH, AhL,
                                                BxH, BxL, BhH, BhL,
                                                bias, cst, OH, OL, nbx, bid);
}

__global__ __launch_bounds__(256, 3) void gemm_fused(
    GArgs a, GArgs b, GArgs sm,
    const float* peInp, const float* peY,
    const float* peW, const float* peB,
    ushort_t* peOh, ushort_t* peOl, int peT,
    int nBigBlk, int nSmBlk)
{
    extern __shared__ __align__(16) ushort_t dsm[];   // 48KB, aliased
    int raw = blockIdx.x;
    if (raw < nBigBlk) {
        int sel = raw >= 1312;
        int local = sel ? raw - 1312 : raw;
        int bid = (local & 7) * 164 + (local >> 3);       // XCD swizzle (1312/8)
        const GArgs& g = sel ? b : a;
        gemm_body<true, 16, 8, 64, 1024, true>(dsm, g.AxH, g.AxL, g.AhH, g.AhL,
                                               g.BxH, g.BxL, g.BhH, g.BhL,
                                               g.bias, g.cst, g.OH, g.OL, 16, bid);
    } else if (raw < nBigBlk + nSmBlk) {
        int local = raw - nBigBlk;                         // 328 small blocks
        int bid = (local & 7) * 41 + (local >> 3);
        gemm_body<false, 8, 8, 64, 256, true>(dsm, sm.AxH, sm.AxL, sm.AhH, sm.AhL,
                                              sm.BxH, sm.BxL, sm.BhH, sm.BhL,
                                              sm.bias, sm.cst, sm.OH, sm.OL, 4, bid);
    } else {
        int local = raw - nBigBlk - nSmBlk;                // 1312 pre0 blocks
        int m = (local % 41) * 256 + (int)threadIdx.x;
        int kg = local / 41;
        float ip0 = 0.f, ip1 = 0.f;
        if (peInp) {
            if (m < ROWS) {
                int bb = m / NNODE, nn = m % NNODE;
                const float* ip = peInp + (((size_t)bb * T_HIST + peT) * NNODE + nn) * 2;
                ip0 = ip[0]; ip1 = ip[1];
            }
        } else {
            ip0 = peY[m];   // dec-form: v = relu(y*w + b); pad rows harmless
        }
        union { ushort_t u[8]; bf16x8 v; } hc, lc;
#pragma unroll
        for (int jj = 0; jj < 8; ++jj) {
            int j = kg * 8 + jj;
            float v;
            if (peInp) v = (m < ROWS) ? fmaxf(ip0 * peW[j] + ip1 * peW[H + j] + peB[j], 0.f) : 0.f;
            else       v = fmaxf(ip0 * peW[j] + peB[j], 0.f);
            split2(v, hc.u[jj], lc.u[jj]);
        }
        size_t base = ((size_t)kg * MPAD + m) * 8;
        *(bf16x8*)&peOh[base] = hc.v;
        *(bf16x8*)&peOl[base] = lc.v;
    }
}

// ---------------------------------------------------------------------------
// Fused projection + decoder pre0 (r14/r15-verified numerics).
// ---------------------------------------------------------------------------
__global__ void proj_pre0_kernel(const ushort_t* __restrict__ xh, const ushort_t* __restrict__ xl,
                                 const float* __restrict__ pw, const float* __restrict__ pb,
                                 const float* __restrict__ w, const float* __restrict__ b,
                                 ushort_t* __restrict__ oh, ushort_t* __restrict__ ol,
                                 float* __restrict__ out, int t) {
    int wid = threadIdx.x >> 6, lane = threadIdx.x & 63;
    int r = blockIdx.x * 4 + wid;
    if (r >= ROWS) return;
    const int kg = lane >> 1, sub = (lane & 1) * 4;
    size_t base = ((size_t)kg * MPAD + r) * 8 + sub;
    float s = 0.f;
#pragma unroll
    for (int q = 0; q < 4; ++q) {
        int k = kg * 8 + sub + q;
        s += (bf2f(xh[base + q]) + bf2f(xl[base + q])) * pw[k];
    }
#pragma unroll
    for (int off = 32; off > 0; off >>= 1) s += __shfl_down(s, off, 64);
    float yv = __shfl(s, 0, 64) + pb[0];
    if (lane == 0) {
        int bb = r / NNODE, n = r % NNODE;
        out[((size_t)bb * T_PRED + t) * NNODE + n] = yv;
    }
    union { ushort_t u[4]; uint2 v; } hs, ls;
#pragma unroll
    for (int q = 0; q < 4; ++q) {
        int k = kg * 8 + sub + q;
        float v = fmaxf(yv * w[k] + b[k], 0.f);
        split2(v, hs.u[q], ls.u[q]);
    }
    *(uint2*)&oh[base] = hs.v;
    *(uint2*)&ol[base] = ls.v;
}

// ---------------------------------------------------------------------------
static inline GArgs mkargs(const ushort_t* xH, const ushort_t* xL,
                           const ushort_t* hH, const ushort_t* hL,
                           ushort_t* const* B, const float* bias, float* c,
                           ushort_t* oH, ushort_t* oL) {
    GArgs g;
    g.AxH = xH; g.AxL = xL; g.AhH = hH; g.AhL = hL;
    g.BxH = B[0]; g.BxL = B[1]; g.BhH = B[2]; g.BhL = B[3];
    g.bias = bias; g.cst = c; g.OH = oH; g.OL = oL;
    return g;
}
static inline GArgs mkargs_small(const ushort_t* aH, const ushort_t* aL,
                                 const ushort_t* bH, const ushort_t* bL,
                                 const float* bias, ushort_t* oH, ushort_t* oL) {
    GArgs g;
    g.AxH = aH; g.AxL = aL; g.AhH = aH; g.AhL = aL;
    g.BxH = bH; g.BxL = bL; g.BhH = bH; g.BhL = bL;
    g.bias = bias; g.cst = nullptr; g.OH = oH; g.OL = oL;
    return g;
}
static inline void big_single(const ushort_t* xH, const ushort_t* xL,
                              const ushort_t* hH, const ushort_t* hL,
                              ushort_t* const* B, const float* bias, float* c,
                              ushort_t* oH, ushort_t* oL, hipStream_t s) {
    gemm_k<true, 16, 8, 64, 1024, 3><<<1312, 256, 0, s>>>(
        xH, xL, hH, hL, B[0], B[1], B[2], B[3], bias, c, oH, oL, 16, 1);
}
static inline void gemm_small(const ushort_t* aH, const ushort_t* aL,
                              const ushort_t* bH, const ushort_t* bL, const float* bias,
                              ushort_t* oH, ushort_t* oL, hipStream_t s) {
    gemm_k<false, 8, 8, 64, 256, 3><<<82 * 4, 256, 0, s>>>(
        aH, aL, aH, aL, bH, bL, bH, bL, bias, nullptr, oH, oL, 4, 1);
}

extern "C" void kernel_launch(void* const* d_in, const int* in_sizes, int n_in,
                              void* d_out, int out_size, void* d_ws, size_t ws_size,
                              hipStream_t stream) {
    (void)in_sizes; (void)n_in; (void)out_size; (void)ws_size;

    const float* inputs      = (const float*)d_in[0];
    // d_in[1..7]: adaptive-supports MLP — dead code (returns identity), skipped.
    const float* enc_pre_w0  = (const float*)d_in[8];
    const float* enc_pre_b0  = (const float*)d_in[9];
    const float* enc_pre_w1  = (const float*)d_in[10];
    const float* enc_pre_b1  = (const float*)d_in[11];
    const float* enc_wih     = (const float*)d_in[12];
    const float* enc_whh     = (const float*)d_in[13];
    const float* enc_bih     = (const float*)d_in[14];
    const float* enc_bhh     = (const float*)d_in[15];
    const float* dec_pre_w0  = (const float*)d_in[16];
    const float* dec_pre_b0  = (const float*)d_in[17];
    const float* dec_pre_w1  = (const float*)d_in[18];
    const float* dec_pre_b1  = (const float*)d_in[19];
    const float* dec_wih     = (const float*)d_in[20];
    const float* dec_whh     = (const float*)d_in[21];
    const float* dec_bih     = (const float*)d_in[22];
    const float* dec_bhh     = (const float*)d_in[23];
    const float* dec_post_w0 = (const float*)d_in[24];
    const float* dec_post_b0 = (const float*)d_in[25];
    const float* dec_post_w1 = (const float*)d_in[26];
    const float* dec_post_b1 = (const float*)d_in[27];
    const float* proj_w      = (const float*)d_in[28];
    const float* proj_b      = (const float*)d_in[29];
    float* out = (float*)d_out;

    char* wsb = (char*)d_ws;
    size_t off = 0;
    auto allocF = [&](size_t n) { float* p = (float*)(wsb + off); off += ((n * 4 + 15) & ~(size_t)15); return p; };
    auto allocU = [&](size_t n) { ushort_t* p = (ushort_t*)(wsb + off); off += ((n * 2 + 15) & ~(size_t)15); return p; };

    const size_t BIGW = (size_t)32 * G4 * 8;
    const size_t SMLW = (size_t)32 * H * 8;
    const size_t ACT  = (size_t)32 * MPAD * 8;

    ushort_t* eB0[4]; ushort_t* eB1[4]; ushort_t* dB0[4]; ushort_t* dB1[4];
    for (int q = 0; q < 4; ++q) eB0[q] = allocU(BIGW);
    for (int q = 0; q < 4; ++q) eB1[q] = allocU(BIGW);
    for (int q = 0; q < 4; ++q) dB0[q] = allocU(BIGW);
    for (int q = 0; q < 4; ++q) dB1[q] = allocU(BIGW);
    float* eBI0 = allocF(G4); float* eBI1 = allocF(G4);
    float* dBI0 = allocF(G4); float* dBI1 = allocF(G4);
    ushort_t* eP1h = allocU(SMLW); ushort_t* eP1l = allocU(SMLW);
    ushort_t* dP1h = allocU(SMLW); ushort_t* dP1l = allocU(SMLW);
    ushort_t* po0h = allocU(SMLW); ushort_t* po0l = allocU(SMLW);
    ushort_t* po1h = allocU(SMLW); ushort_t* po1l = allocU(SMLW);
    float* encW0eff = allocF(2 * H);
    float* decPre0eff = allocF(H);
    ushort_t* h0H[2]; ushort_t* h0L[2]; ushort_t* h1H[2]; ushort_t* h1L[2];
    for (int q = 0; q < 2; ++q) { h0H[q] = allocU(ACT); h0L[q] = allocU(ACT); }
    for (int q = 0; q < 2; ++q) { h1H[q] = allocU(ACT); h1L[q] = allocU(ACT); }
    float* c0 = allocF((size_t)H * MPAD);
    float* c1 = allocF((size_t)H * MPAD);
    ushort_t* xaH[2]; ushort_t* xaL[2]; ushort_t* xbH[2]; ushort_t* xbL[2];
    for (int q = 0; q < 2; ++q) { xaH[q] = allocU(ACT); xaL[q] = allocU(ACT); }
    for (int q = 0; q < 2; ++q) { xbH[q] = allocU(ACT); xbL[q] = allocU(ACT); }
    float* y = allocF(MPAD);

    const size_t LOFF = (size_t)G4 * H;
    const int EW = 256;

    // ---- weight prep ----
    pack_big_kernel<<<128, EW, 0, stream>>>(enc_wih, enc_whh, enc_bih, enc_bhh,
                                            eB0[0], eB0[1], eB0[2], eB0[3], eBI0);
    pack_big_kernel<<<128, EW, 0, stream>>>(enc_wih + LOFF, enc_whh + LOFF, enc_bih + G4, enc_bhh + G4,
                                            eB1[0], eB1[1], eB1[2], eB1[3], eBI1);
    pack_big_kernel<<<128, EW, 0, stream>>>(dec_wih, dec_whh, dec_bih, dec_bhh,
                                            dB0[0], dB0[1], dB0[2], dB0[3], dBI0);
    pack_big_kernel<<<128, EW, 0, stream>>>(dec_wih + LOFF, dec_whh + LOFF, dec_bih + G4, dec_bhh + G4,
                                            dB1[0], dB1[1], dB1[2], dB1[3], dBI1);
    pack_small_kernel<<<32, EW, 0, stream>>>(enc_pre_w1, eP1h, eP1l);
    pack_small_kernel<<<32, EW, 0, stream>>>(dec_pre_w1, dP1h, dP1l);
    pack_small_kernel<<<32, EW, 0, stream>>>(dec_post_w0, po0h, po0l);
    pack_small_kernel<<<32, EW, 0, stream>>>(dec_post_w1, po1h, po1l);
    collapse_kernel<<<2, EW, 0, stream>>>(enc_pre_w0, encW0eff, 2, 5);
    collapse_kernel<<<1, EW, 0, stream>>>(dec_pre_w0, decPre0eff, 1, 5);

    // ---- init state ----
    for (int q = 0; q < 2; ++q) {
        hipMemsetAsync(h0H[q], 0, ACT * 2, stream); hipMemsetAsync(h0L[q], 0, ACT * 2, stream);
        hipMemsetAsync(h1H[q], 0, ACT * 2, stream); hipMemsetAsync(h1L[q], 0, ACT * 2, stream);
    }
    hipMemsetAsync(c0, 0, (size_t)H * MPAD * 4, stream);
    hipMemsetAsync(c1, 0, (size_t)H * MPAD * 4, stream);
    hipMemsetAsync(y, 0, (size_t)MPAD * 4, stream);

    const dim3 PG(MPAD / 256, 32);
    GArgs gDummy = {};   // value-init (r18 lesson: memset resolves to device fn)

    // ---- encoder ----
    // Parity (r16/r17-audited): pre0(t)/small(t) use xa/xb slot (t&1).
    // pair4(t) = {L1(t), L0(t+1), small(t+2), pre0(t+3)}: pre0(t+3) writes
    // xa[pr^1] (last reader small(t+1) in pair(t-1) — done); small(t+2) reads
    // xa[pr]; GEMM segments touch only h0/h1/xb. All disjoint.
    enc_pre0_pk<<<PG, EW, 0, stream>>>(inputs, encW0eff, enc_pre_b0, xaH[0], xaL[0], 0);
    gemm_small(xaH[0], xaL[0], eP1h, eP1l, enc_pre_b1, xbH[0], xbL[0], stream);
    enc_pre0_pk<<<PG, EW, 0, stream>>>(inputs, encW0eff, enc_pre_b0, xaH[1], xaL[1], 1);
    gemm_small(xaH[1], xaL[1], eP1h, eP1l, enc_pre_b1, xbH[1], xbL[1], stream);
    {
        // fused {L0(0), pre0(2)}: L0(0) reads xb[0], h0[0] -> h0[1];
        // pre0(2) -> xa[0] (small(0) done).
        GArgs gL0 = mkargs(xbH[0], xbL[0], h0H[0], h0L[0], eB0, eBI0, c0, h0H[1], h0L[1]);
        gemm_fused<<<1312 + 1312, 256, 49152, stream>>>(
            gL0, gL0, gDummy, inputs, nullptr, encW0eff, enc_pre_b0,
            xaH[0], xaL[0], 2, 1312, 0);
    }
    for (int t = 0; t < T_HIST - 1; ++t) {
        int pr = t & 1;
        GArgs gL1 = mkargs(h0H[pr ^ 1], h0L[pr ^ 1], h1H[pr], h1L[pr],
                           eB1, eBI1, c1, h1H[pr ^ 1], h1L[pr ^ 1]);
        GArgs gL0 = mkargs(xbH[pr ^ 1], xbL[pr ^ 1], h0H[pr ^ 1], h0L[pr ^ 1],
                           eB0, eBI0, c0, h0H[pr], h0L[pr]);
        bool hasSm  = (t + 2 <= T_HIST - 1);
        bool hasPre = (t + 3 <= T_HIST - 1);
        GArgs gSm = hasSm ? mkargs_small(xaH[pr], xaL[pr], eP1h, eP1l, enc_pre_b1,
                                         xbH[pr], xbL[pr])
                          : gDummy;
        int grid = 2624 + (hasSm ? 328 : 0) + (hasPre ? 1312 : 0);
        gemm_fused<<<grid, 256, 49152, stream>>>(
            gL1, gL0, gSm, inputs, nullptr, encW0eff, enc_pre_b0,
            xaH[pr ^ 1], xaL[pr ^ 1], t + 3, 2624, hasSm ? 328 : 0);
    }
    {
        // fused {L1(11), dec_pre0}: L1(11) reads h0[0], h1[1] -> h1[0];
        // dec_pre0 (y==0) -> xa[0] (encoder xa[0] last read by small(10) in
        // pair(8) — done). Decoder aliases xa/xb slot 0.
        GArgs gL1 = mkargs(h0H[0], h0L[0], h1H[1], h1L[1], eB1, eBI1, c1, h1H[0], h1L[0]);
        gemm_fused<<<1312 + 1312, 256, 49152, stream>>>(
            gL1, gL1, gDummy, nullptr, y, decPre0eff, dec_pre_b0,
            xaH[0], xaL[0], 0, 1312, 0);
    }

    // ---- decoder (strictly sequential; aliases xa/xb slot 0) ----
    for (int d = 0; d < T_PRED; ++d) {
        int pr = d & 1;
        gemm_small(xaH[0], xaL[0], dP1h, dP1l, dec_pre_b1, xbH[0], xbL[0], stream);
        big_single(xbH[0], xbL[0], h0H[pr], h0L[pr], dB0, dBI0, c0,
                   h0H[pr ^ 1], h0L[pr ^ 1], stream);
        big_single(h0H[pr ^ 1], h0L[pr ^ 1], h1H[pr], h1L[pr], dB1, dBI1, c1,
                   h1H[pr ^ 1], h1L[pr ^ 1], stream);
        gemm_small(h1H[pr ^ 1], h1L[pr ^ 1], po0h, po0l, dec_post_b0, xaH[0], xaL[0], stream);
        gemm_small(xaH[0], xaL[0], po1h, po1l, dec_post_b1, xbH[0], xbL[0], stream);
        proj_pre0_kernel<<<(ROWS + 3) / 4, EW, 0, stream>>>(
            xbH[0], xbL[0], proj_w, proj_b, decPre0eff, dec_pre_b0, xaH[0], xaL[0], out, d);
    }
}

// Round 20
// 2244.224 us; speedup vs baseline: 1.3041x; 1.0039x over previous
//
#include <hip/hip_runtime.h>
#include <math.h>

#define BATCH 32
#define NNODE 325
#define T_HIST 12
#define T_PRED 12
#define H 256
#define G4 1024
#define ROWS (BATCH*NNODE)
#define MPAD 10496  // 82*128

typedef __attribute__((ext_vector_type(8))) short bf16x8;
typedef __attribute__((ext_vector_type(4))) float f32x4;
typedef unsigned short ushort_t;
typedef unsigned int uint_t;

#define GLL16(gp, sp) __builtin_amdgcn_global_load_lds( \
    (const __attribute__((address_space(1))) void*)(gp), \
    (__attribute__((address_space(3))) void*)(sp), 16, 0, 0)

__device__ inline float bf2f(ushort_t u) { return __uint_as_float(((uint_t)u) << 16); }

__device__ inline void split2(float v, ushort_t& h, ushort_t& l) {
    uint_t b = __float_as_uint(v);
    uint_t hb = (b + 0x7fffu + ((b >> 16) & 1u)) & 0xffff0000u;
    h = (ushort_t)(hb >> 16);
    float r = v - __uint_as_float(hb);
    uint_t rb = __float_as_uint(r);
    l = (ushort_t)((rb + 0x7fffu + ((rb >> 16) & 1u)) >> 16);
}

__device__ inline float sigm(float x) {
    x = fminf(fmaxf(x, -30.f), 30.f);
    return 1.f / (1.f + __expf(-x));
}
__device__ inline float tanh_f(float x) {
    x = fminf(fmaxf(x, -15.f), 15.f);
    float e = __expf(2.f * x);
    return (e - 1.f) / (e + 1.f);
}

// ---------------------------------------------------------------------------
// Weight prep
// ---------------------------------------------------------------------------
__global__ void collapse_kernel(const float* __restrict__ w, float* __restrict__ out,
                                int cin, int nblk) {
    int idx = blockIdx.x * blockDim.x + threadIdx.x;
    if (idx >= cin * H) return;
    int c = idx / H, h = idx % H;
    float s = 0.f;
    for (int k = 0; k < nblk; ++k) s += w[(size_t)(k * cin + c) * H + h];
    out[idx] = s;
}

// Gate-interleaved big pack: col' = 4*j + gate. Layout [32 kg][1024 col'][8].
__global__ void pack_big_kernel(const float* __restrict__ wih, const float* __restrict__ whh,
                                const float* __restrict__ bih, const float* __restrict__ bhh,
                                ushort_t* __restrict__ Bxh, ushort_t* __restrict__ Bxl,
                                ushort_t* __restrict__ Bhh, ushort_t* __restrict__ Bhl,
                                float* __restrict__ biasI) {
    int idx = blockIdx.x * blockDim.x + threadIdx.x;  // 32*1024
    if (idx >= 32 * G4) return;
    int kg = idx >> 10, col = idx & 1023;
    int j = col >> 2, g = col & 3;
    int gcol = g * 256 + j;
    if (kg == 0) biasI[col] = bih[gcol] + bhh[gcol];
#pragma unroll
    for (int jj = 0; jj < 8; ++jj) {
        int k = kg * 8 + jj;
        ushort_t hh, ll;
        split2(wih[(size_t)gcol * H + k], hh, ll);
        Bxh[(size_t)idx * 8 + jj] = hh; Bxl[(size_t)idx * 8 + jj] = ll;
        split2(whh[(size_t)gcol * H + k], hh, ll);
        Bhh[(size_t)idx * 8 + jj] = hh; Bhl[(size_t)idx * 8 + jj] = ll;
    }
}

// Small pack: collapse 5 K-blocks, layout [32 kg][256 n][8] hi/lo.
__global__ void pack_small_kernel(const float* __restrict__ w,
                                  ushort_t* __restrict__ Bh, ushort_t* __restrict__ Bl) {
    int idx = blockIdx.x * blockDim.x + threadIdx.x;  // 32*256
    if (idx >= 32 * H) return;
    int kg = idx >> 8, n = idx & 255;
#pragma unroll
    for (int jj = 0; jj < 8; ++jj) {
        int k = kg * 8 + jj;
        float s = 0.f;
        for (int blk = 0; blk < 5; ++blk) s += w[(size_t)(blk * H + k) * H + n];
        ushort_t hh, ll; split2(s, hh, ll);
        Bh[(size_t)idx * 8 + jj] = hh; Bl[(size_t)idx * 8 + jj] = ll;
    }
}

// ---------------------------------------------------------------------------
// Producers writing k-packed [kg][MPAD][8] hi/lo
// ---------------------------------------------------------------------------
__global__ void enc_pre0_pk(const float* __restrict__ inp, const float* __restrict__ w,
                            const float* __restrict__ b, ushort_t* __restrict__ oh,
                            ushort_t* __restrict__ ol, int t) {
    int m = blockIdx.x * 256 + threadIdx.x;   // grid (41, 32)
    int kg = blockIdx.y;
    float ip0 = 0.f, ip1 = 0.f;
    if (m < ROWS) {
        int bb = m / NNODE, nn = m % NNODE;
        const float* ip = inp + (((size_t)bb * T_HIST + t) * NNODE + nn) * 2;
        ip0 = ip[0]; ip1 = ip[1];
    }
    union { ushort_t u[8]; bf16x8 v; } hc, lc;
#pragma unroll
    for (int jj = 0; jj < 8; ++jj) {
        int j = kg * 8 + jj;
        float v = (m < ROWS) ? fmaxf(ip0 * w[j] + ip1 * w[H + j] + b[j], 0.f) : 0.f;
        split2(v, hc.u[jj], lc.u[jj]);
    }
    size_t base = ((size_t)kg * MPAD + m) * 8;
    *(bf16x8*)&oh[base] = hc.v;
    *(bf16x8*)&ol[base] = lc.v;
}

// ---------------------------------------------------------------------------
// r6 GEMM body, factored; LDS passed in (aliasing across instantiations —
// round-16 lesson: static __shared__ per instantiation SUMS). Layout:
// As[2][2][4096] at 0 (32KB), Bs[2][2][1024] at 16384 (16KB). PRIO: setprio
// around MFMA (deep-grid fused kernels only). Tile 128x64, 4 waves; 2-slot
// ring; raw s_barrier + counted vmcnt(6).
// Swapped operands mfma(B,A): acc[i][j][r]: m = bm+wm*64+i*16+(lane&15),
//   n = bn+wn*32+j*16+(lane>>4)*4+r.
// GATES: gate-interleaved cols (col'=4cell+g) => r-quad = one cell's i,f,g,o.
// ---------------------------------------------------------------------------
template<bool GATES, int NSC, int HSC, int BNT, int NBG, bool PRIO>
__device__ __forceinline__ void gemm_body(
    ushort_t* smem,
    const ushort_t* AxH, const ushort_t* AxL,
    const ushort_t* AhH, const ushort_t* AhL,
    const ushort_t* BxH, const ushort_t* BxL,
    const ushort_t* BhH, const ushort_t* BhL,
    const float* bias, float* cst,
    ushort_t* OH, ushort_t* OL,
    int nbx, int bid)
{
    constexpr int BCH = BNT * 4;        // B chunks per slot (=256)
    constexpr int JB  = BNT / 32;       // 16-col frags per wave (=2)
    ushort_t* Asp = smem;                      // 16384 ushorts = 32KB
    ushort_t* Bsp = smem + 16384;              //  8192 ushorts = 16KB
    auto As = [&](int slot, int hl) { return Asp + (slot * 2 + hl) * 4096; };
    auto Bs = [&](int slot, int hl) { return Bsp + (slot * 2 + hl) * (BCH * 8); };

    const int bm = (bid / nbx) * 128, bn = (bid % nbx) * BNT;
    const int tid = threadIdx.x, lane = tid & 63;
    const int wm = (tid >> 7) & 1, wn = (tid >> 6) & 1;
    const int l15 = lane & 15, lk = lane >> 4;

    auto stageSC = [&](int s, int slot) {
        const ushort_t *Ah, *Al, *Bh, *Bl; int ck;
        if (s < HSC) { Ah = AxH; Al = AxL; Bh = BxH; Bl = BxL; ck = s; }
        else         { Ah = AhH; Al = AhL; Bh = BhH; Bl = BhL; ck = s - HSC; }
#pragma unroll
        for (int q = 0; q < 2; ++q) {
            int ubase = (tid & 192) + q * 256;
            int u = ubase + lane;
            int kgl = u >> 7, rc = u & 127;
            size_t ga = ((size_t)(ck * 4 + kgl) * MPAD + bm + rc) * 8;
            GLL16(Ah + ga, As(slot, 0) + ubase * 8);
            GLL16(Al + ga, As(slot, 1) + ubase * 8);
        }
        {
            int ubase = tid & 192;
            int kgl = tid >> 6, nc = tid & 63;
            size_t gb = ((size_t)(ck * 4 + kgl) * NBG + bn + nc) * 8;
            GLL16(Bh + gb, Bs(slot, 0) + ubase * 8);
            GLL16(Bl + gb, Bs(slot, 1) + ubase * 8);
        }
    };

    f32x4 acc[4][JB] = {};

    stageSC(0, 0);   // prologue: 6 gll/thread outstanding

#pragma unroll
    for (int s = 0; s < NSC; ++s) {
        __builtin_amdgcn_s_barrier();            // compute(s-1) done -> slot free
        if (s + 1 < NSC) {
            stageSC(s + 1, (s + 1) & 1);
            asm volatile("s_waitcnt vmcnt(6)" ::: "memory");  // SC(s) landed
        } else {
            asm volatile("s_waitcnt vmcnt(0)" ::: "memory");
        }
        __builtin_amdgcn_s_barrier();            // SC(s) visible to all waves
        __builtin_amdgcn_sched_barrier(0);

        const int slot = s & 1;
        bf16x8 ah[4], al[4], bh[JB], bl[JB];
#pragma unroll
        for (int i = 0; i < 4; ++i) {
            int ea = (lk * 128 + wm * 64 + i * 16 + l15) * 8;
            ah[i] = *(const bf16x8*)(As(slot, 0) + ea);
            al[i] = *(const bf16x8*)(As(slot, 1) + ea);
        }
#pragma unroll
        for (int j = 0; j < JB; ++j) {
            int eb = (lk * BNT + wn * (BNT / 2) + j * 16 + l15) * 8;
            bh[j] = *(const bf16x8*)(Bs(slot, 0) + eb);
            bl[j] = *(const bf16x8*)(Bs(slot, 1) + eb);
        }
        if constexpr (PRIO) __builtin_amdgcn_s_setprio(1);
#pragma unroll
        for (int i = 0; i < 4; ++i)
#pragma unroll
            for (int j = 0; j < JB; ++j)
                acc[i][j] = __builtin_amdgcn_mfma_f32_16x16x32_bf16(bh[j], ah[i], acc[i][j], 0, 0, 0);
#pragma unroll
        for (int i = 0; i < 4; ++i)
#pragma unroll
            for (int j = 0; j < JB; ++j)
                acc[i][j] = __builtin_amdgcn_mfma_f32_16x16x32_bf16(bl[j], ah[i], acc[i][j], 0, 0, 0);
#pragma unroll
        for (int i = 0; i < 4; ++i)
#pragma unroll
            for (int j = 0; j < JB; ++j)
                acc[i][j] = __builtin_amdgcn_mfma_f32_16x16x32_bf16(bh[j], al[i], acc[i][j], 0, 0, 0);
        if constexpr (PRIO) __builtin_amdgcn_s_setprio(0);
    }

    // ---- epilogue ----
    if constexpr (GATES) {
        uint_t* Hs = (uint_t*)smem;   // 8.7KB scratch; last K step read slot 1
        const int jb0 = (bn >> 2) + wn * 8;
#pragma unroll
        for (int j = 0; j < JB; ++j) {
            float4 b4 = *(const float4*)&bias[bn + wn * 32 + j * 16 + lk * 4];
            int cell = jb0 + j * 4 + lk;
#pragma unroll
            for (int i = 0; i < 4; ++i) {
                int m = bm + wm * 64 + i * 16 + l15;
                float vi = acc[i][j][0] + b4.x;
                float vf = acc[i][j][1] + b4.y;
                float vg = acc[i][j][2] + b4.z;
                float vo = acc[i][j][3] + b4.w;
                size_t ci = (size_t)cell * MPAD + m;
                float cold = cst[ci];
                float cn = sigm(vf) * cold + sigm(vi) * tanh_f(vg);
                float hn = sigm(vo) * tanh_f(cn);
                cst[ci] = cn;
                ushort_t hh, hl; split2(hn, hh, hl);
                Hs[(wm * 64 + i * 16 + l15) * 17 + wn * 8 + j * 4 + lk] = ((uint_t)hh << 16) | hl;
            }
        }
        __syncthreads();
        {
            int mloc = tid & 127, kgl = tid >> 7;   // 2 kg x 128 rows
            union { ushort_t u[8]; bf16x8 v; } hi, lo;
#pragma unroll
            for (int jj = 0; jj < 8; ++jj) {
                uint_t wv = Hs[mloc * 17 + kgl * 8 + jj];
                hi.u[jj] = (ushort_t)(wv >> 16);
                lo.u[jj] = (ushort_t)(wv & 0xffffu);
            }
            size_t base = ((size_t)((bn >> 5) + kgl) * MPAD + bm + mloc) * 8;
            *(bf16x8*)&OH[base] = hi.v;
            *(bf16x8*)&OL[base] = lo.v;
        }
    } else {
#pragma unroll
        for (int j = 0; j < JB; ++j) {
            float4 b4 = *(const float4*)&bias[bn + wn * (BNT / 2) + j * 16 + lk * 4];
#pragma unroll
            for (int i = 0; i < 4; ++i) {
                float v0 = fmaxf(acc[i][j][0] + b4.x, 0.f);
                float v1 = fmaxf(acc[i][j][1] + b4.y, 0.f);
                float v2 = fmaxf(acc[i][j][2] + b4.z, 0.f);
                float v3 = fmaxf(acc[i][j][3] + b4.w, 0.f);
                ushort_t h0, h1, h2, h3, l0, l1, l2, l3;
                split2(v0, h0, l0); split2(v1, h1, l1);
                split2(v2, h2, l2); split2(v3, h3, l3);
                uint_t hu0 = (uint_t)h0 | ((uint_t)h1 << 16), hu1 = (uint_t)h2 | ((uint_t)h3 << 16);
                uint_t lu0 = (uint_t)l0 | ((uint_t)l1 << 16), lu1 = (uint_t)l2 | ((uint_t)l3 << 16);
                uint_t ph0 = (uint_t)__shfl_xor((int)hu0, 16, 64);
                uint_t ph1 = (uint_t)__shfl_xor((int)hu1, 16, 64);
                uint_t pl0 = (uint_t)__shfl_xor((int)lu0, 16, 64);
                uint_t pl1 = (uint_t)__shfl_xor((int)lu1, 16, 64);
                int kgg = ((bn + wn * (BNT / 2) + j * 16) >> 3) + (lk >> 1);
                size_t base = ((size_t)kgg * MPAD + bm + wm * 64 + i * 16 + l15) * 8;
                union { uint_t u2[4]; bf16x8 v; } ch;
                if ((lk & 1) == 0) {
                    ch.u2[0] = hu0; ch.u2[1] = hu1; ch.u2[2] = ph0; ch.u2[3] = ph1;
                    *(bf16x8*)&OH[base] = ch.v;
                } else {
                    ch.u2[0] = pl0; ch.u2[1] = pl1; ch.u2[2] = lu0; ch.u2[3] = lu1;
                    *(bf16x8*)&OL[base] = ch.v;
                }
            }
        }
    }
}

// ---------------------------------------------------------------------------
// Kernels. Singles: static 48KB LDS, direct args, NO setprio (r6-verified).
// gemm_fused: up to 4 segments {big a, big b, small, pre0} in one dispatch,
// ONE aliased dynamic-LDS buffer (48KB), setprio ON for GEMM segments.
// Segment layout: [0,nBigBlk) bigs (a then b), [nBigBlk, +nSmBlk) small,
// rest = 1312 pre0 blocks. nBigBlk may be 0 (small+pre0 only dispatch).
// ---------------------------------------------------------------------------
struct GArgs {
    const ushort_t *AxH, *AxL, *AhH, *AhL;
    const ushort_t *BxH, *BxL, *BhH, *BhL;
    const float* bias;
    float* cst;
    ushort_t *OH, *OL;
};

template<bool GATES, int NSC, int HSC, int BNT, int NBG, int MINW>
__global__ __launch_bounds__(256, MINW) void gemm_k(
    const ushort_t* __restrict__ AxH, const ushort_t* __restrict__ AxL,
    const ushort_t* __restrict__ AhH, const ushort_t* __restrict__ AhL,
    const ushort_t* __restrict__ BxH, const ushort_t* __restrict__ BxL,
    const ushort_t* __restrict__ BhH, const ushort_t* __restrict__ BhL,
    const float* __restrict__ bias, float* __restrict__ cst,
    ushort_t* __restrict__ OH, ushort_t* __restrict__ OL,
    int nbx, int doSwz)
{
    __shared__ __align__(16) ushort_t smem[24576];   // 48KB
    int bid = blockIdx.x;
    if (doSwz) { int cpx = gridDim.x >> 3; bid = (bid & 7) * cpx + (bid >> 3); }
    gemm_body<GATES, NSC, HSC, BNT, NBG, false>(smem, AxH, AxL, AhH, AhL,
                                                BxH, BxL, BhH, BhL,
                                                bias, cst, OH, OL, nbx, bid);
}

__global__ __launch_bounds__(256, 3) void gemm_fused(
    GArgs a, GArgs b, GArgs sm,
    const float* peInp, const float* peY,
    const float* peW, const float* peB,
    ushort_t* peOh, ushort_t* peOl, int peT,
    int nBigBlk, int nSmBlk)
{
    extern __shared__ __align__(16) ushort_t dsm[];   // 48KB, aliased
    int raw = blockIdx.x;
    if (raw < nBigBlk) {
        int sel = raw >= 1312;
        int local = sel ? raw - 1312 : raw;
        int bid = (local & 7) * 164 + (local >> 3);       // XCD swizzle (1312/8)
        const GArgs& g = sel ? b : a;
        gemm_body<true, 16, 8, 64, 1024, true>(dsm, g.AxH, g.AxL, g.AhH, g.AhL,
                                               g.BxH, g.BxL, g.BhH, g.BhL,
                                               g.bias, g.cst, g.OH, g.OL, 16, bid);
    } else if (raw < nBigBlk + nSmBlk) {
        int local = raw - nBigBlk;                         // 328 small blocks
        int bid = (local & 7) * 41 + (local >> 3);
        gemm_body<false, 8, 8, 64, 256, true>(dsm, sm.AxH, sm.AxL, sm.AhH, sm.AhL,
                                              sm.BxH, sm.BxL, sm.BhH, sm.BhL,
                                              sm.bias, sm.cst, sm.OH, sm.OL, 4, bid);
    } else {
        int local = raw - nBigBlk - nSmBlk;                // 1312 pre0 blocks
        int m = (local % 41) * 256 + (int)threadIdx.x;
        int kg = local / 41;
        float ip0 = 0.f, ip1 = 0.f;
        if (peInp) {
            if (m < ROWS) {
                int bb = m / NNODE, nn = m % NNODE;
                const float* ip = peInp + (((size_t)bb * T_HIST + peT) * NNODE + nn) * 2;
                ip0 = ip[0]; ip1 = ip[1];
            }
        } else {
            ip0 = peY[m];   // dec-form: v = relu(y*w + b); pad rows harmless
        }
        union { ushort_t u[8]; bf16x8 v; } hc, lc;
#pragma unroll
        for (int jj = 0; jj < 8; ++jj) {
            int j = kg * 8 + jj;
            float v;
            if (peInp) v = (m < ROWS) ? fmaxf(ip0 * peW[j] + ip1 * peW[H + j] + peB[j], 0.f) : 0.f;
            else       v = fmaxf(ip0 * peW[j] + peB[j], 0.f);
            split2(v, hc.u[jj], lc.u[jj]);
        }
        size_t base = ((size_t)kg * MPAD + m) * 8;
        *(bf16x8*)&peOh[base] = hc.v;
        *(bf16x8*)&peOl[base] = lc.v;
    }
}

// ---------------------------------------------------------------------------
// Fused projection + decoder pre0 (r14/r15-verified numerics).
// ---------------------------------------------------------------------------
__global__ void proj_pre0_kernel(const ushort_t* __restrict__ xh, const ushort_t* __restrict__ xl,
                                 const float* __restrict__ pw, const float* __restrict__ pb,
                                 const float* __restrict__ w, const float* __restrict__ b,
                                 ushort_t* __restrict__ oh, ushort_t* __restrict__ ol,
                                 float* __restrict__ out, int t) {
    int wid = threadIdx.x >> 6, lane = threadIdx.x & 63;
    int r = blockIdx.x * 4 + wid;
    if (r >= ROWS) return;
    const int kg = lane >> 1, sub = (lane & 1) * 4;
    size_t base = ((size_t)kg * MPAD + r) * 8 + sub;
    float s = 0.f;
#pragma unroll
    for (int q = 0; q < 4; ++q) {
        int k = kg * 8 + sub + q;
        s += (bf2f(xh[base + q]) + bf2f(xl[base + q])) * pw[k];
    }
#pragma unroll
    for (int off = 32; off > 0; off >>= 1) s += __shfl_down(s, off, 64);
    float yv = __shfl(s, 0, 64) + pb[0];
    if (lane == 0) {
        int bb = r / NNODE, n = r % NNODE;
        out[((size_t)bb * T_PRED + t) * NNODE + n] = yv;
    }
    union { ushort_t u[4]; uint2 v; } hs, ls;
#pragma unroll
    for (int q = 0; q < 4; ++q) {
        int k = kg * 8 + sub + q;
        float v = fmaxf(yv * w[k] + b[k], 0.f);
        split2(v, hs.u[q], ls.u[q]);
    }
    *(uint2*)&oh[base] = hs.v;
    *(uint2*)&ol[base] = ls.v;
}

// ---------------------------------------------------------------------------
static inline GArgs mkargs(const ushort_t* xH, const ushort_t* xL,
                           const ushort_t* hH, const ushort_t* hL,
                           ushort_t* const* B, const float* bias, float* c,
                           ushort_t* oH, ushort_t* oL) {
    GArgs g;
    g.AxH = xH; g.AxL = xL; g.AhH = hH; g.AhL = hL;
    g.BxH = B[0]; g.BxL = B[1]; g.BhH = B[2]; g.BhL = B[3];
    g.bias = bias; g.cst = c; g.OH = oH; g.OL = oL;
    return g;
}
static inline GArgs mkargs_small(const ushort_t* aH, const ushort_t* aL,
                                 const ushort_t* bH, const ushort_t* bL,
                                 const float* bias, ushort_t* oH, ushort_t* oL) {
    GArgs g;
    g.AxH = aH; g.AxL = aL; g.AhH = aH; g.AhL = aL;
    g.BxH = bH; g.BxL = bL; g.BhH = bH; g.BhL = bL;
    g.bias = bias; g.cst = nullptr; g.OH = oH; g.OL = oL;
    return g;
}
static inline void big_single(const ushort_t* xH, const ushort_t* xL,
                              const ushort_t* hH, const ushort_t* hL,
                              ushort_t* const* B, const float* bias, float* c,
                              ushort_t* oH, ushort_t* oL, hipStream_t s) {
    gemm_k<true, 16, 8, 64, 1024, 3><<<1312, 256, 0, s>>>(
        xH, xL, hH, hL, B[0], B[1], B[2], B[3], bias, c, oH, oL, 16, 1);
}
static inline void gemm_small(const ushort_t* aH, const ushort_t* aL,
                              const ushort_t* bH, const ushort_t* bL, const float* bias,
                              ushort_t* oH, ushort_t* oL, hipStream_t s) {
    gemm_k<false, 8, 8, 64, 256, 3><<<82 * 4, 256, 0, s>>>(
        aH, aL, aH, aL, bH, bL, bH, bL, bias, nullptr, oH, oL, 4, 1);
}

extern "C" void kernel_launch(void* const* d_in, const int* in_sizes, int n_in,
                              void* d_out, int out_size, void* d_ws, size_t ws_size,
                              hipStream_t stream) {
    (void)in_sizes; (void)n_in; (void)out_size; (void)ws_size;

    const float* inputs      = (const float*)d_in[0];
    // d_in[1..7]: adaptive-supports MLP — dead code (returns identity), skipped.
    const float* enc_pre_w0  = (const float*)d_in[8];
    const float* enc_pre_b0  = (const float*)d_in[9];
    const float* enc_pre_w1  = (const float*)d_in[10];
    const float* enc_pre_b1  = (const float*)d_in[11];
    const float* enc_wih     = (const float*)d_in[12];
    const float* enc_whh     = (const float*)d_in[13];
    const float* enc_bih     = (const float*)d_in[14];
    const float* enc_bhh     = (const float*)d_in[15];
    const float* dec_pre_w0  = (const float*)d_in[16];
    const float* dec_pre_b0  = (const float*)d_in[17];
    const float* dec_pre_w1  = (const float*)d_in[18];
    const float* dec_pre_b1  = (const float*)d_in[19];
    const float* dec_wih     = (const float*)d_in[20];
    const float* dec_whh     = (const float*)d_in[21];
    const float* dec_bih     = (const float*)d_in[22];
    const float* dec_bhh     = (const float*)d_in[23];
    const float* dec_post_w0 = (const float*)d_in[24];
    const float* dec_post_b0 = (const float*)d_in[25];
    const float* dec_post_w1 = (const float*)d_in[26];
    const float* dec_post_b1 = (const float*)d_in[27];
    const float* proj_w      = (const float*)d_in[28];
    const float* proj_b      = (const float*)d_in[29];
    float* out = (float*)d_out;

    char* wsb = (char*)d_ws;
    size_t off = 0;
    auto allocF = [&](size_t n) { float* p = (float*)(wsb + off); off += ((n * 4 + 15) & ~(size_t)15); return p; };
    auto allocU = [&](size_t n) { ushort_t* p = (ushort_t*)(wsb + off); off += ((n * 2 + 15) & ~(size_t)15); return p; };

    const size_t BIGW = (size_t)32 * G4 * 8;
    const size_t SMLW = (size_t)32 * H * 8;
    const size_t ACT  = (size_t)32 * MPAD * 8;

    ushort_t* eB0[4]; ushort_t* eB1[4]; ushort_t* dB0[4]; ushort_t* dB1[4];
    for (int q = 0; q < 4; ++q) eB0[q] = allocU(BIGW);
    for (int q = 0; q < 4; ++q) eB1[q] = allocU(BIGW);
    for (int q = 0; q < 4; ++q) dB0[q] = allocU(BIGW);
    for (int q = 0; q < 4; ++q) dB1[q] = allocU(BIGW);
    float* eBI0 = allocF(G4); float* eBI1 = allocF(G4);
    float* dBI0 = allocF(G4); float* dBI1 = allocF(G4);
    ushort_t* eP1h = allocU(SMLW); ushort_t* eP1l = allocU(SMLW);
    ushort_t* dP1h = allocU(SMLW); ushort_t* dP1l = allocU(SMLW);
    ushort_t* po0h = allocU(SMLW); ushort_t* po0l = allocU(SMLW);
    ushort_t* po1h = allocU(SMLW); ushort_t* po1l = allocU(SMLW);
    float* encW0eff = allocF(2 * H);
    float* decPre0eff = allocF(H);
    ushort_t* h0H[2]; ushort_t* h0L[2]; ushort_t* h1H[2]; ushort_t* h1L[2];
    for (int q = 0; q < 2; ++q) { h0H[q] = allocU(ACT); h0L[q] = allocU(ACT); }
    for (int q = 0; q < 2; ++q) { h1H[q] = allocU(ACT); h1L[q] = allocU(ACT); }
    float* c0 = allocF((size_t)H * MPAD);
    float* c1 = allocF((size_t)H * MPAD);
    ushort_t* xaH[2]; ushort_t* xaL[2]; ushort_t* xbH[2]; ushort_t* xbL[2];
    for (int q = 0; q < 2; ++q) { xaH[q] = allocU(ACT); xaL[q] = allocU(ACT); }
    for (int q = 0; q < 2; ++q) { xbH[q] = allocU(ACT); xbL[q] = allocU(ACT); }
    float* y = allocF(MPAD);

    const size_t LOFF = (size_t)G4 * H;
    const int EW = 256;

    // ---- weight prep ----
    pack_big_kernel<<<128, EW, 0, stream>>>(enc_wih, enc_whh, enc_bih, enc_bhh,
                                            eB0[0], eB0[1], eB0[2], eB0[3], eBI0);
    pack_big_kernel<<<128, EW, 0, stream>>>(enc_wih + LOFF, enc_whh + LOFF, enc_bih + G4, enc_bhh + G4,
                                            eB1[0], eB1[1], eB1[2], eB1[3], eBI1);
    pack_big_kernel<<<128, EW, 0, stream>>>(dec_wih, dec_whh, dec_bih, dec_bhh,
                                            dB0[0], dB0[1], dB0[2], dB0[3], dBI0);
    pack_big_kernel<<<128, EW, 0, stream>>>(dec_wih + LOFF, dec_whh + LOFF, dec_bih + G4, dec_bhh + G4,
                                            dB1[0], dB1[1], dB1[2], dB1[3], dBI1);
    pack_small_kernel<<<32, EW, 0, stream>>>(enc_pre_w1, eP1h, eP1l);
    pack_small_kernel<<<32, EW, 0, stream>>>(dec_pre_w1, dP1h, dP1l);
    pack_small_kernel<<<32, EW, 0, stream>>>(dec_post_w0, po0h, po0l);
    pack_small_kernel<<<32, EW, 0, stream>>>(dec_post_w1, po1h, po1l);
    collapse_kernel<<<2, EW, 0, stream>>>(enc_pre_w0, encW0eff, 2, 5);
    collapse_kernel<<<1, EW, 0, stream>>>(dec_pre_w0, decPre0eff, 1, 5);

    // ---- init state ----
    for (int q = 0; q < 2; ++q) {
        hipMemsetAsync(h0H[q], 0, ACT * 2, stream); hipMemsetAsync(h0L[q], 0, ACT * 2, stream);
        hipMemsetAsync(h1H[q], 0, ACT * 2, stream); hipMemsetAsync(h1L[q], 0, ACT * 2, stream);
    }
    hipMemsetAsync(c0, 0, (size_t)H * MPAD * 4, stream);
    hipMemsetAsync(c1, 0, (size_t)H * MPAD * 4, stream);
    hipMemsetAsync(y, 0, (size_t)MPAD * 4, stream);

    const dim3 PG(MPAD / 256, 32);
    GArgs gDummy = {};   // value-init (r18 lesson: memset resolves to device fn)

    // ---- encoder head (3 dispatches; r19 used 5) ----
    // D1: pre0(0) -> xa[0].
    // D2: fused{small(0): xa[0]->xb[0], pre0(1)->xa[1]} — independent.
    // D3: fused{L0(0): xb[0],h0[0]->h0[1]; small(1): xa[1]->xb[1];
    //           pre0(2)->xa[0] (last reader small(0) done in D2)} — disjoint.
    enc_pre0_pk<<<PG, EW, 0, stream>>>(inputs, encW0eff, enc_pre_b0, xaH[0], xaL[0], 0);
    {
        GArgs gSm0 = mkargs_small(xaH[0], xaL[0], eP1h, eP1l, enc_pre_b1,
                                  xbH[0], xbL[0]);
        gemm_fused<<<328 + 1312, 256, 49152, stream>>>(
            gDummy, gDummy, gSm0, inputs, nullptr, encW0eff, enc_pre_b0,
            xaH[1], xaL[1], 1, 0, 328);
    }
    {
        GArgs gL0 = mkargs(xbH[0], xbL[0], h0H[0], h0L[0], eB0, eBI0, c0, h0H[1], h0L[1]);
        GArgs gSm1 = mkargs_small(xaH[1], xaL[1], eP1h, eP1l, enc_pre_b1,
                                  xbH[1], xbL[1]);
        gemm_fused<<<1312 + 328 + 1312, 256, 49152, stream>>>(
            gL0, gL0, gSm1, inputs, nullptr, encW0eff, enc_pre_b0,
            xaH[0], xaL[0], 2, 1312, 328);
    }
    // ---- encoder main loop (r19-verified pair4) ----
    // pair4(t) = {L1(t), L0(t+1), small(t+2), pre0(t+3)} — parity-audited.
    for (int t = 0; t < T_HIST - 1; ++t) {
        int pr = t & 1;
        GArgs gL1 = mkargs(h0H[pr ^ 1], h0L[pr ^ 1], h1H[pr], h1L[pr],
                           eB1, eBI1, c1, h1H[pr ^ 1], h1L[pr ^ 1]);
        GArgs gL0 = mkargs(xbH[pr ^ 1], xbL[pr ^ 1], h0H[pr ^ 1], h0L[pr ^ 1],
                           eB0, eBI0, c0, h0H[pr], h0L[pr]);
        bool hasSm  = (t + 2 <= T_HIST - 1);
        bool hasPre = (t + 3 <= T_HIST - 1);
        GArgs gSm = hasSm ? mkargs_small(xaH[pr], xaL[pr], eP1h, eP1l, enc_pre_b1,
                                         xbH[pr], xbL[pr])
                          : gDummy;
        int grid = 2624 + (hasSm ? 328 : 0) + (hasPre ? 1312 : 0);
        gemm_fused<<<grid, 256, 49152, stream>>>(
            gL1, gL0, gSm, inputs, nullptr, encW0eff, enc_pre_b0,
            xaH[pr ^ 1], xaL[pr ^ 1], t + 3, 2624, hasSm ? 328 : 0);
    }
    {
        // fused {L1(11), dec_pre0}: L1(11) reads h0[0], h1[1] -> h1[0];
        // dec_pre0 (y==0) -> xa[0]. Decoder aliases xa/xb slot 0.
        GArgs gL1 = mkargs(h0H[0], h0L[0], h1H[1], h1L[1], eB1, eBI1, c1, h1H[0], h1L[0]);
        gemm_fused<<<1312 + 1312, 256, 49152, stream>>>(
            gL1, gL1, gDummy, nullptr, y, decPre0eff, dec_pre_b0,
            xaH[0], xaL[0], 0, 1312, 0);
    }

    // ---- decoder (strictly sequential; aliases xa/xb slot 0) ----
    for (int d = 0; d < T_PRED; ++d) {
        int pr = d & 1;
        gemm_small(xaH[0], xaL[0], dP1h, dP1l, dec_pre_b1, xbH[0], xbL[0], stream);
        big_single(xbH[0], xbL[0], h0H[pr], h0L[pr], dB0, dBI0, c0,
                   h0H[pr ^ 1], h0L[pr ^ 1], stream);
        big_single(h0H[pr ^ 1], h0L[pr ^ 1], h1H[pr], h1L[pr], dB1, dBI1, c1,
                   h1H[pr ^ 1], h1L[pr ^ 1], stream);
        gemm_small(h1H[pr ^ 1], h1L[pr ^ 1], po0h, po0l, dec_post_b0, xaH[0], xaL[0], stream);
        gemm_small(xaH[0], xaL[0], po1h, po1l, dec_post_b1, xbH[0], xbL[0], stream);
        proj_pre0_kernel<<<(ROWS + 3) / 4, EW, 0, stream>>>(
            xbH[0], xbL[0], proj_w, proj_b, decPre0eff, dec_pre_b0, xaH[0], xaL[0], out, d);
    }
}